// Round 3
// baseline (212.370 us; speedup 1.0000x reference)
//
#include <hip/hip_runtime.h>
#include <stdint.h>
#include <math.h>

// PhysicsForwardModel: B=2, Nz=Nx=128, Ly=Lx=512.
// out[b,t,l] = (1/3) * sum_j Cy[j,l] * sum_k cos(F[k,j]*t) * a[k] * (Cy[:,:128] x[b] Cy[:,128:256]^T)[k,j]
//              + std_b * N(0,1)  (JAX threefry key=42, partitionable counters, XLA erfinv)
// R12: revert stageB to the verified R10 fused form (R11's uniform-VMEM inner loops were
//      latency-bound: stageC 66us @ VALUBusy 7%). Changes:
//  - cyt_kernel precomputes CyT[n][k]=cy_elem(2n+1,k,sc(k)) (bit-identical exprs); stageB
//    phases A/B load it coalesced instead of computing 34M cos (same accumulation order).
//  - stageB also folds the CyC[j][l] stageC-coefficient table (verified in R11).
//  - stageC = register-tiled GEMM: thread owns 1t x 4l x 2b; per j one float4 CyC load +
//    two 16B-window Vt loads + 8 fmaf; unroll 8. Per-output j-chain identical -> bit-same out.

#define HALF_N 262144  // 512*512 per-batch elements
#define PI_F 3.14159274101257324f

// ws layout (floats):
//   Vt      [0      .. 524288)   [j][b][t]
//   CyC     [524288 .. 786432)   [j][l] stageC coefficient (scale folded)
//   CyT     [786432 .. 917504)   [n][k] = cy_elem(2n+1, k, sc(k)), n<256
//   partial [917504 .. 918528)   256 blocks x {s0,q0,s1,q1}

__device__ __forceinline__ uint32_t rotl32(uint32_t v, int r) {
  return (v << r) | (v >> (32 - r));
}

// XLA ErfInv32 (Giles) -- matches reference's lax.erf_inv
__device__ __forceinline__ float erfinv_xla(float x) {
  float w = -log1pf(__fmul_rn(-x, x));
  float p;
  if (w < 5.0f) {
    w = w - 2.5f;
    p = 2.81022636e-08f;
    p = fmaf(p, w, 3.43273939e-07f);
    p = fmaf(p, w, -3.5233877e-06f);
    p = fmaf(p, w, -4.39150654e-06f);
    p = fmaf(p, w, 0.00021858087f);
    p = fmaf(p, w, -0.00125372503f);
    p = fmaf(p, w, -0.00417768164f);
    p = fmaf(p, w, 0.246640727f);
    p = fmaf(p, w, 1.50140941f);
  } else {
    w = __fsqrt_rn(w) - 3.0f;
    p = -0.000200214257f;
    p = fmaf(p, w, 0.000100950558f);
    p = fmaf(p, w, 0.00134934322f);
    p = fmaf(p, w, -0.00367342844f);
    p = fmaf(p, w, 0.00573950773f);
    p = fmaf(p, w, -0.0076224613f);
    p = fmaf(p, w, 0.00943887047f);
    p = fmaf(p, w, 1.00167406f);
    p = fmaf(p, w, 2.83297682f);
  }
  return p * x;
}

// Cy[k,n] = sc(k) * 2 * cos(pi*(2n+1)*k/1024), with n2p1 = (float)(2n+1) exact
__device__ __forceinline__ float cy_elem(float n2p1, float kf, float sc) {
  float t1 = __fmul_rn(PI_F, n2p1);
  float arg = __fmul_rn(t1, kf) * (1.0f / 1024.0f);
  return __fmul_rn(sc, __fmul_rn(2.0f, __cosf(arg)));
}

// CyT[n][k] = cy_elem(2n+1, k, sc(k)); n = blockIdx (256), k = tid (512).
__global__ __launch_bounds__(512) void cyt_kernel(float* __restrict__ CyT) {
  int n = blockIdx.x;
  int k = threadIdx.x;
  float kf = (float)k;
  float sc = (k == 0) ? (1.0f / __fsqrt_rn(2048.0f)) : 0.03125f;
  CyT[(n << 9) + k] = cy_elem((float)(2 * n + 1), kf, sc);
}

// fusedB, block = j (grid 512, 512 threads):
//   CyC fold:     CyC[j][tid] = stageC coefficient (bit-identical expr to R10 stageC)
//   A  (tid<128): cyl[jj] = CyT[128+jj][j]  (== Cy[j,128+jj])
//   A2 (tid<256): us[b*128+i] = sum_jj x[b,i,jj]*cyl[jj]
//   B  (lane=k):  msf[2k+b] = a[k] * sum_i CyT[i][k]*us[b,i]; fs[k] = F[k,j]
//   C  (lane=t):  Vt[j,b,t] = sum_k cos(fs[k]*t) * msf[2k+b]
__global__ __launch_bounds__(512, 4) void stageB_kernel(const float* __restrict__ x,
                                                        const float* __restrict__ CyT,
                                                        float* __restrict__ Vt,
                                                        float* __restrict__ CyC) {
  __shared__ float cyl[128];
  __shared__ float us[256];
  __shared__ float fs[512];
  __shared__ float msf[1024];
  int j = blockIdx.x;
  int tid = threadIdx.x;
  float jf = (float)j;
  // CyC[j][l], l = tid. Bit-identical to R10 stageC's on-the-fly coefficients.
  {
    float c;
    if (j == 0) {
      c = __fmul_rn(1.0f / __fsqrt_rn(2048.0f), 2.0f);
    } else {
      float t1 = __fmul_rn(PI_F, (float)(2 * tid + 1));
      c = __fmul_rn(0.0625f, __cosf(__fmul_rn(t1, jf) * (1.0f / 1024.0f)));
    }
    CyC[(j << 9) + tid] = c;
  }
  if (tid < 128) {
    cyl[tid] = CyT[((128 + tid) << 9) + j];
  }
  __syncthreads();
  if (tid < 256) {
    int b = tid >> 7, i = tid & 127;
    const float* xr = x + (b * 128 + i) * 128;
    float accA = 0.0f, accB = 0.0f;
    for (int jj = 0; jj < 128; jj += 8) {
      float4 xa = *(const float4*)&xr[jj];
      float4 xb = *(const float4*)&xr[jj + 4];
      float4 ca = *(const float4*)&cyl[jj];
      float4 cb = *(const float4*)&cyl[jj + 4];
      accA = fmaf(xa.x, ca.x, accA); accB = fmaf(xa.y, ca.y, accB);
      accA = fmaf(xa.z, ca.z, accA); accB = fmaf(xa.w, ca.w, accB);
      accA = fmaf(xb.x, cb.x, accA); accB = fmaf(xb.y, cb.y, accB);
      accA = fmaf(xb.z, cb.z, accA); accB = fmaf(xb.w, cb.w, accB);
    }
    us[tid] = accA + accB;
  }
  __syncthreads();
  {
    float a = CyT[tid];  // n=0: a[k] = Cy[k,0]
    float acc0 = __fmul_rn(a, us[0]);
    float acc1 = __fmul_rn(a, us[128]);
    float accA0 = 0.f, accA1 = 0.f;
    {
      float c1 = CyT[(1 << 9) + tid];
      float c2 = CyT[(2 << 9) + tid];
      float c3 = CyT[(3 << 9) + tid];
      acc0 = fmaf(c1, us[1], acc0);   acc1 = fmaf(c1, us[129], acc1);
      accA0 = fmaf(c2, us[2], accA0); accA1 = fmaf(c2, us[130], accA1);
      acc0 = fmaf(c3, us[3], acc0);   acc1 = fmaf(c3, us[131], acc1);
    }
    for (int i = 4; i < 128; i += 4) {
      float c0 = CyT[((i + 0) << 9) + tid];
      float c1 = CyT[((i + 1) << 9) + tid];
      float c2 = CyT[((i + 2) << 9) + tid];
      float c3 = CyT[((i + 3) << 9) + tid];
      float4 u0 = *(const float4*)&us[i];
      float4 u1 = *(const float4*)&us[128 + i];
      acc0 = fmaf(c0, u0.x, acc0);   acc1 = fmaf(c0, u1.x, acc1);
      accA0 = fmaf(c1, u0.y, accA0); accA1 = fmaf(c1, u1.y, accA1);
      acc0 = fmaf(c2, u0.z, acc0);   acc1 = fmaf(c2, u1.z, acc1);
      accA0 = fmaf(c3, u0.w, accA0); accA1 = fmaf(c3, u1.w, accA1);
    }
    acc0 += accA0;
    acc1 += accA1;
    float kf = (float)tid;
    const float w0 = PI_F / 512.0f;  // exact pow2 scale of pi_f
    float ky = __fmul_rn(kf, w0);
    float kx = __fmul_rn(jf, w0);
    fs[tid] = __fsqrt_rn(__fadd_rn(__fmul_rn(ky, ky), __fmul_rn(kx, kx)));
    msf[2 * tid] = __fmul_rn(a, acc0);
    msf[2 * tid + 1] = __fmul_rn(a, acc1);
  }
  __syncthreads();
  float tf = (float)tid;
  float acc0 = 0.f, acc1 = 0.f, acc2 = 0.f, acc3 = 0.f;
  for (int k0 = 0; k0 < 512; k0 += 8) {
    float4 f0 = *(const float4*)&fs[k0];
    float4 f1 = *(const float4*)&fs[k0 + 4];
    float4 m0 = *(const float4*)&msf[2 * k0];
    float4 m1 = *(const float4*)&msf[2 * k0 + 4];
    float4 m2 = *(const float4*)&msf[2 * k0 + 8];
    float4 m3 = *(const float4*)&msf[2 * k0 + 12];
    float ph0 = __cosf(__fmul_rn(f0.x, tf));  // arg bit-matches ref's f32 F*t
    float ph1 = __cosf(__fmul_rn(f0.y, tf));
    float ph2 = __cosf(__fmul_rn(f0.z, tf));
    float ph3 = __cosf(__fmul_rn(f0.w, tf));
    float ph4 = __cosf(__fmul_rn(f1.x, tf));
    float ph5 = __cosf(__fmul_rn(f1.y, tf));
    float ph6 = __cosf(__fmul_rn(f1.z, tf));
    float ph7 = __cosf(__fmul_rn(f1.w, tf));
    acc0 = fmaf(ph0, m0.x, acc0); acc1 = fmaf(ph0, m0.y, acc1);
    acc2 = fmaf(ph1, m0.z, acc2); acc3 = fmaf(ph1, m0.w, acc3);
    acc0 = fmaf(ph2, m1.x, acc0); acc1 = fmaf(ph2, m1.y, acc1);
    acc2 = fmaf(ph3, m1.z, acc2); acc3 = fmaf(ph3, m1.w, acc3);
    acc0 = fmaf(ph4, m2.x, acc0); acc1 = fmaf(ph4, m2.y, acc1);
    acc2 = fmaf(ph5, m2.z, acc2); acc3 = fmaf(ph5, m2.w, acc3);
    acc0 = fmaf(ph6, m3.x, acc0); acc1 = fmaf(ph6, m3.y, acc1);
    acc2 = fmaf(ph7, m3.z, acc2); acc3 = fmaf(ph7, m3.w, acc3);
  }
  Vt[(j << 10) + tid] = acc0 + acc2;
  Vt[(j << 10) + 512 + tid] = acc1 + acc3;
}

// stageC: register-tiled GEMM. Grid 256 = 32 t-tiles(16) x 8 l-tiles(64); 256 threads.
// Thread (tx=tid&15, ty=tid>>4): t = t0+ty, l = l0+4*tx; owns 1t x 4l x 2b outputs.
// Per j: CyC float4 (coalesced 256B/wave) + 2 Vt dwords (16B window broadcast) + 8 fmaf.
// Per-output j-chain identical to R10/R11 (fmaf ascending j, then /3) -> bit-identical out.
__global__ __launch_bounds__(256, 8) void stageC_kernel(const float* __restrict__ Vt,
                                                        const float* __restrict__ CyC,
                                                        float* __restrict__ out,
                                                        float* __restrict__ partial) {
  int bid = blockIdx.x;
  int t0 = (bid >> 3) << 4;
  int l0 = (bid & 7) << 6;
  int tid = threadIdx.x;
  int tx = tid & 15, ty = tid >> 4;
  int t = t0 + ty;
  int l = l0 + (tx << 2);
  float a0 = 0.f, a1 = 0.f, a2 = 0.f, a3 = 0.f;  // b0, l..l+3
  float b0 = 0.f, b1 = 0.f, b2 = 0.f, b3 = 0.f;  // b1, l..l+3
#pragma unroll 8
  for (int j = 0; j < 512; ++j) {
    float4 c = *(const float4*)&CyC[(j << 9) + l];
    float v0 = Vt[(j << 10) + t];
    float v1 = Vt[(j << 10) + 512 + t];
    a0 = fmaf(c.x, v0, a0); a1 = fmaf(c.y, v0, a1);
    a2 = fmaf(c.z, v0, a2); a3 = fmaf(c.w, v0, a3);
    b0 = fmaf(c.x, v1, b0); b1 = fmaf(c.y, v1, b1);
    b2 = fmaf(c.z, v1, b2); b3 = fmaf(c.w, v1, b3);
  }
  float p0 = a0 / 3.0f, p1 = a1 / 3.0f, p2 = a2 / 3.0f, p3 = a3 / 3.0f;
  float r0 = b0 / 3.0f, r1 = b1 / 3.0f, r2 = b2 / 3.0f, r3 = b3 / 3.0f;
  *(float4*)&out[(t << 9) + l] = make_float4(p0, p1, p2, p3);
  *(float4*)&out[HALF_N + (t << 9) + l] = make_float4(r0, r1, r2, r3);
  // stats: per-thread partials over its 8 outputs, then wave+block reduce
  float s0 = ((p0 + p1) + (p2 + p3));
  float q0 = (fmaf(p0, p0, p1 * p1) + fmaf(p2, p2, p3 * p3));
  float s1 = ((r0 + r1) + (r2 + r3));
  float q1 = (fmaf(r0, r0, r1 * r1) + fmaf(r2, r2, r3 * r3));
  for (int off = 32; off > 0; off >>= 1) {
    s0 += __shfl_down(s0, off);
    q0 += __shfl_down(q0, off);
    s1 += __shfl_down(s1, off);
    q1 += __shfl_down(q1, off);
  }
  __shared__ float red[4][4];
  int wave = tid >> 6;
  if ((tid & 63) == 0) {
    red[wave][0] = s0; red[wave][1] = q0; red[wave][2] = s1; red[wave][3] = q1;
  }
  __syncthreads();
  if (tid == 0) {
    float c0 = 0.f, c1 = 0.f, c2 = 0.f, c3 = 0.f;
    for (int wv = 0; wv < 4; ++wv) {
      c0 += red[wv][0]; c1 += red[wv][1]; c2 += red[wv][2]; c3 += red[wv][3];
    }
    partial[bid * 4 + 0] = c0;
    partial[bid * 4 + 1] = c1;
    partial[bid * 4 + 2] = c2;
    partial[bid * 4 + 3] = c3;
  }
}

// Fused stats + noise: redundant partial reduce (256 quads) -> (std0,std1), then threefry noise.
// element i -> threefry2x32(key=(0,42), ctr=(0,i)), bits = o0^o1
__global__ __launch_bounds__(256) void noise_kernel(float* __restrict__ out,
                                                    const float* __restrict__ partial) {
  int tid = threadIdx.x;
  const float4* pq = (const float4*)partial;  // 256 quads {s0,q0,s1,q1}
  float4 pa = pq[tid];
  float s0 = pa.x, q0 = pa.y, s1 = pa.z, q1 = pa.w;
  for (int off = 32; off > 0; off >>= 1) {
    s0 += __shfl_down(s0, off);
    q0 += __shfl_down(q0, off);
    s1 += __shfl_down(s1, off);
    q1 += __shfl_down(q1, off);
  }
  __shared__ float red[4][4];
  int wave = tid >> 6;
  if ((tid & 63) == 0) {
    red[wave][0] = s0; red[wave][1] = q0; red[wave][2] = s1; red[wave][3] = q1;
  }
  __syncthreads();
  float S = red[0][0] + red[1][0] + red[2][0] + red[3][0];
  float Q = red[0][1] + red[1][1] + red[2][1] + red[3][1];
  float S2 = red[0][2] + red[1][2] + red[2][2] + red[3][2];
  float Q2 = red[0][3] + red[1][3] + red[2][3] + red[3][3];
  const float invN = 1.0f / 262144.0f;
  float m0 = S * invN, m1 = S2 * invN;
  float std0 = __fsqrt_rn(fmaxf(Q * invN - m0 * m0, 0.0f));
  float std1 = __fsqrt_rn(fmaxf(Q2 * invN - m1 * m1, 0.0f));

  int i = blockIdx.x * 256 + tid;  // < 524288
  uint32_t x0 = 0u;
  uint32_t x1 = (uint32_t)i;
  const uint32_t k0 = 0u, k1 = 42u;
  const uint32_t k2 = k0 ^ k1 ^ 0x1BD11BDAu;
  x0 += k0; x1 += k1;
#define QR(r) x0 += x1; x1 = rotl32(x1, r); x1 ^= x0;
  QR(13) QR(15) QR(26) QR(6)
  x0 += k1; x1 += k2 + 1u;
  QR(17) QR(29) QR(16) QR(24)
  x0 += k2; x1 += k0 + 2u;
  QR(13) QR(15) QR(26) QR(6)
  x0 += k0; x1 += k1 + 3u;
  QR(17) QR(29) QR(16) QR(24)
  x0 += k1; x1 += k2 + 4u;
  QR(13) QR(15) QR(26) QR(6)
  x0 += k2; x1 += k0 + 5u;
#undef QR
  uint32_t bits = x0 ^ x1;
  const float lo = __uint_as_float(0xBF7FFFFFu);  // nextafter(-1,0)
  float f = __uint_as_float((bits >> 9) | 0x3F800000u) - 1.0f;
  float u = fmaxf(lo, __fadd_rn(__fmul_rn(f, 2.0f), lo));
  const float sqrt2 = 1.41421356237309515f;
  out[i] += (i < HALF_N ? std0 : std1) * (sqrt2 * erfinv_xla(u));
}

extern "C" void kernel_launch(void* const* d_in, const int* in_sizes, int n_in,
                              void* d_out, int out_size, void* d_ws, size_t ws_size,
                              hipStream_t stream) {
  const float* x = (const float*)d_in[0];
  float* ws = (float*)d_ws;
  float* Vt      = ws;
  float* CyC     = ws + 524288;
  float* CyT     = ws + 786432;
  float* partial = ws + 917504;
  float* out = (float*)d_out;

  cyt_kernel<<<256, 512, 0, stream>>>(CyT);
  stageB_kernel<<<512, 512, 0, stream>>>(x, CyT, Vt, CyC);
  stageC_kernel<<<256, 256, 0, stream>>>(Vt, CyC, out, partial);
  noise_kernel<<<2048, 256, 0, stream>>>(out, partial);
}

// Round 4
// 136.698 us; speedup vs baseline: 1.5536x; 1.5536x over previous
//
#include <hip/hip_runtime.h>
#include <stdint.h>
#include <math.h>

// PhysicsForwardModel: B=2, Nz=Nx=128, Ly=Lx=512.
// out[b,t,l] = (1/3) * sum_j Cy[j,l] * sum_k cos(F[k,j]*t) * a[k] * (Cy[:,:128] x[b] Cy[:,128:256]^T)[k,j]
//              + std_b * N(0,1)  (JAX threefry key=42, partitionable counters, XLA erfinv)
// R13: R10 structure restored (R11/R12 uniform-VMEM & low-occupancy tiling were latency-bound;
//      CyT table made stageB worse via 268MB L2/L3 streaming). Two amortizations:
//  - stageB: 256 threads/block; thread owns 2 k's (phase B) and 2 t's (phase C). Halves the
//    per-CU ds_read_b128 broadcast cost (the R1-counter bottleneck); cos/fma totals unchanged;
//    per-k and per-t chains bit-identical -> bit-identical Vt. cy_elem computes (no tables).
//  - stageC: R10 vq[j][4] LDS staging kept, but coefficients from the CyC table (folded into
//    stageB, ~free) instead of 512 cos/thread, and thread owns 2 l's -> per j: 1 broadcast
//    b128 + 2 coalesced b32 + 8 fma. Grid 256 x 256thr. Per-output j-chains identical.

#define HALF_N 262144  // 512*512 per-batch elements
#define PI_F 3.14159274101257324f

// ws layout (floats):
//   Vt      [0      .. 524288)   [j][b][t]
//   CyC     [524288 .. 786432)   [j][l] stageC coefficient (scale folded)
//   partial [786432 .. 787456)   256 blocks x {s0,q0,s1,q1}

__device__ __forceinline__ uint32_t rotl32(uint32_t v, int r) {
  return (v << r) | (v >> (32 - r));
}

// XLA ErfInv32 (Giles) -- matches reference's lax.erf_inv
__device__ __forceinline__ float erfinv_xla(float x) {
  float w = -log1pf(__fmul_rn(-x, x));
  float p;
  if (w < 5.0f) {
    w = w - 2.5f;
    p = 2.81022636e-08f;
    p = fmaf(p, w, 3.43273939e-07f);
    p = fmaf(p, w, -3.5233877e-06f);
    p = fmaf(p, w, -4.39150654e-06f);
    p = fmaf(p, w, 0.00021858087f);
    p = fmaf(p, w, -0.00125372503f);
    p = fmaf(p, w, -0.00417768164f);
    p = fmaf(p, w, 0.246640727f);
    p = fmaf(p, w, 1.50140941f);
  } else {
    w = __fsqrt_rn(w) - 3.0f;
    p = -0.000200214257f;
    p = fmaf(p, w, 0.000100950558f);
    p = fmaf(p, w, 0.00134934322f);
    p = fmaf(p, w, -0.00367342844f);
    p = fmaf(p, w, 0.00573950773f);
    p = fmaf(p, w, -0.0076224613f);
    p = fmaf(p, w, 0.00943887047f);
    p = fmaf(p, w, 1.00167406f);
    p = fmaf(p, w, 2.83297682f);
  }
  return p * x;
}

// Cy[k,n] = sc(k) * 2 * cos(pi*(2n+1)*k/1024), with n2p1 = (float)(2n+1) exact
__device__ __forceinline__ float cy_elem(float n2p1, float kf, float sc) {
  float t1 = __fmul_rn(PI_F, n2p1);
  float arg = __fmul_rn(t1, kf) * (1.0f / 1024.0f);
  return __fmul_rn(sc, __fmul_rn(2.0f, __cosf(arg)));
}

// fusedB, block = j (grid 512, 256 threads):
//   CyC fold:     CyC[j][l] for l=tid,tid+256 (bit-identical expr to R10 stageC coeffs)
//   A  (tid<128): cyl[jj] = Cy[j,128+jj]
//   A2 (all 256): us[b*128+i] = sum_jj x[b,i,jj]*cyl[jj]
//   B  (k=tid,tid+256): msf[2k+b] = a[k]*sum_i Cy[k,i]*us[b,i]; fs[k] = F[k,j]
//   C  (t=tid,tid+256): Vt[j,b,t] = sum_k cos(fs[k]*t)*msf[2k+b]
__global__ __launch_bounds__(256, 4) void stageB_kernel(const float* __restrict__ x,
                                                        float* __restrict__ Vt,
                                                        float* __restrict__ CyC) {
  __shared__ float cyl[128];
  __shared__ float us[256];
  __shared__ float fs[512];
  __shared__ float msf[1024];
  int j = blockIdx.x;
  int tid = threadIdx.x;
  float jf = (float)j;
  // CyC[j][l] for l = tid and tid+256. Bit-identical to R10 stageC's on-the-fly coefficients.
  if (j == 0) {
    float c = __fmul_rn(1.0f / __fsqrt_rn(2048.0f), 2.0f);
    CyC[tid] = c;
    CyC[tid + 256] = c;
  } else {
    float t1a = __fmul_rn(PI_F, (float)(2 * tid + 1));
    float t1b = __fmul_rn(PI_F, (float)(2 * (tid + 256) + 1));
    CyC[(j << 9) + tid] = __fmul_rn(0.0625f, __cosf(__fmul_rn(t1a, jf) * (1.0f / 1024.0f)));
    CyC[(j << 9) + tid + 256] = __fmul_rn(0.0625f, __cosf(__fmul_rn(t1b, jf) * (1.0f / 1024.0f)));
  }
  if (tid < 128) {
    float scj = (j == 0) ? (1.0f / __fsqrt_rn(2048.0f)) : 0.03125f;
    cyl[tid] = cy_elem((float)(2 * (128 + tid) + 1), jf, scj);
  }
  __syncthreads();
  {
    int b = tid >> 7, i = tid & 127;
    const float* xr = x + (b * 128 + i) * 128;
    float accA = 0.0f, accB = 0.0f;
    for (int jj = 0; jj < 128; jj += 8) {
      float4 xa = *(const float4*)&xr[jj];
      float4 xb = *(const float4*)&xr[jj + 4];
      float4 ca = *(const float4*)&cyl[jj];
      float4 cb = *(const float4*)&cyl[jj + 4];
      accA = fmaf(xa.x, ca.x, accA); accB = fmaf(xa.y, ca.y, accB);
      accA = fmaf(xa.z, ca.z, accA); accB = fmaf(xa.w, ca.w, accB);
      accA = fmaf(xb.x, cb.x, accA); accB = fmaf(xb.y, cb.y, accB);
      accA = fmaf(xb.z, cb.z, accA); accB = fmaf(xb.w, cb.w, accB);
    }
    us[tid] = accA + accB;
  }
  __syncthreads();
  for (int kk = 0; kk < 2; ++kk) {
    int k = tid + (kk << 8);
    float kf = (float)k;
    float sc = (k == 0) ? (1.0f / __fsqrt_rn(2048.0f)) : 0.03125f;
    float a = cy_elem(1.0f, kf, sc);  // i=0: a[k] = Cy[k,0]
    float acc0 = __fmul_rn(a, us[0]);
    float acc1 = __fmul_rn(a, us[128]);
    float accA0 = 0.f, accA1 = 0.f;
    {
      float c1 = cy_elem(3.0f, kf, sc);
      float c2 = cy_elem(5.0f, kf, sc);
      float c3 = cy_elem(7.0f, kf, sc);
      acc0 = fmaf(c1, us[1], acc0);   acc1 = fmaf(c1, us[129], acc1);
      accA0 = fmaf(c2, us[2], accA0); accA1 = fmaf(c2, us[130], accA1);
      acc0 = fmaf(c3, us[3], acc0);   acc1 = fmaf(c3, us[131], acc1);
    }
    for (int i = 4; i < 128; i += 4) {
      float b0 = (float)(2 * i + 1);
      float c0 = cy_elem(b0, kf, sc);
      float c1 = cy_elem(__fadd_rn(b0, 2.0f), kf, sc);
      float c2 = cy_elem(__fadd_rn(b0, 4.0f), kf, sc);
      float c3 = cy_elem(__fadd_rn(b0, 6.0f), kf, sc);
      float4 u0 = *(const float4*)&us[i];
      float4 u1 = *(const float4*)&us[128 + i];
      acc0 = fmaf(c0, u0.x, acc0);   acc1 = fmaf(c0, u1.x, acc1);
      accA0 = fmaf(c1, u0.y, accA0); accA1 = fmaf(c1, u1.y, accA1);
      acc0 = fmaf(c2, u0.z, acc0);   acc1 = fmaf(c2, u1.z, acc1);
      accA0 = fmaf(c3, u0.w, accA0); accA1 = fmaf(c3, u1.w, accA1);
    }
    acc0 += accA0;
    acc1 += accA1;
    const float w0 = PI_F / 512.0f;  // exact pow2 scale of pi_f
    float ky = __fmul_rn(kf, w0);
    float kx = __fmul_rn(jf, w0);
    fs[k] = __fsqrt_rn(__fadd_rn(__fmul_rn(ky, ky), __fmul_rn(kx, kx)));
    msf[2 * k] = __fmul_rn(a, acc0);
    msf[2 * k + 1] = __fmul_rn(a, acc1);
  }
  __syncthreads();
  // Phase C: thread owns t = tid and t2 = tid+256. Per-t chains identical to R10.
  float tf0 = (float)tid;
  float tf1 = (float)(tid + 256);
  float e0 = 0.f, e1 = 0.f, e2 = 0.f, e3 = 0.f;  // t = tid
  float g0 = 0.f, g1 = 0.f, g2 = 0.f, g3 = 0.f;  // t = tid+256
  for (int k0 = 0; k0 < 512; k0 += 8) {
    float4 f0 = *(const float4*)&fs[k0];
    float4 f1 = *(const float4*)&fs[k0 + 4];
    float4 m0 = *(const float4*)&msf[2 * k0];
    float4 m1 = *(const float4*)&msf[2 * k0 + 4];
    float4 m2 = *(const float4*)&msf[2 * k0 + 8];
    float4 m3 = *(const float4*)&msf[2 * k0 + 12];
    float pa0 = __cosf(__fmul_rn(f0.x, tf0));  // arg bit-matches ref's f32 F*t
    float pa1 = __cosf(__fmul_rn(f0.y, tf0));
    float pa2 = __cosf(__fmul_rn(f0.z, tf0));
    float pa3 = __cosf(__fmul_rn(f0.w, tf0));
    float pa4 = __cosf(__fmul_rn(f1.x, tf0));
    float pa5 = __cosf(__fmul_rn(f1.y, tf0));
    float pa6 = __cosf(__fmul_rn(f1.z, tf0));
    float pa7 = __cosf(__fmul_rn(f1.w, tf0));
    float pb0 = __cosf(__fmul_rn(f0.x, tf1));
    float pb1 = __cosf(__fmul_rn(f0.y, tf1));
    float pb2 = __cosf(__fmul_rn(f0.z, tf1));
    float pb3 = __cosf(__fmul_rn(f0.w, tf1));
    float pb4 = __cosf(__fmul_rn(f1.x, tf1));
    float pb5 = __cosf(__fmul_rn(f1.y, tf1));
    float pb6 = __cosf(__fmul_rn(f1.z, tf1));
    float pb7 = __cosf(__fmul_rn(f1.w, tf1));
    e0 = fmaf(pa0, m0.x, e0); e1 = fmaf(pa0, m0.y, e1);
    e2 = fmaf(pa1, m0.z, e2); e3 = fmaf(pa1, m0.w, e3);
    e0 = fmaf(pa2, m1.x, e0); e1 = fmaf(pa2, m1.y, e1);
    e2 = fmaf(pa3, m1.z, e2); e3 = fmaf(pa3, m1.w, e3);
    e0 = fmaf(pa4, m2.x, e0); e1 = fmaf(pa4, m2.y, e1);
    e2 = fmaf(pa5, m2.z, e2); e3 = fmaf(pa5, m2.w, e3);
    e0 = fmaf(pa6, m3.x, e0); e1 = fmaf(pa6, m3.y, e1);
    e2 = fmaf(pa7, m3.z, e2); e3 = fmaf(pa7, m3.w, e3);
    g0 = fmaf(pb0, m0.x, g0); g1 = fmaf(pb0, m0.y, g1);
    g2 = fmaf(pb1, m0.z, g2); g3 = fmaf(pb1, m0.w, g3);
    g0 = fmaf(pb2, m1.x, g0); g1 = fmaf(pb2, m1.y, g1);
    g2 = fmaf(pb3, m1.z, g2); g3 = fmaf(pb3, m1.w, g3);
    g0 = fmaf(pb4, m2.x, g0); g1 = fmaf(pb4, m2.y, g1);
    g2 = fmaf(pb5, m2.z, g2); g3 = fmaf(pb5, m2.w, g3);
    g0 = fmaf(pb6, m3.x, g0); g1 = fmaf(pb6, m3.y, g1);
    g2 = fmaf(pb7, m3.z, g2); g3 = fmaf(pb7, m3.w, g3);
  }
  Vt[(j << 10) + tid] = e0 + e2;
  Vt[(j << 10) + tid + 256] = g0 + g2;
  Vt[(j << 10) + 512 + tid] = e1 + e3;
  Vt[(j << 10) + 512 + tid + 256] = g1 + g3;
}

// stageC: block = t-pair (grid 256, 256 threads); thread owns l = tid and tid+256.
//   out[b,t,l] = (1/3) * sum_j CyC[j,l] * Vt[j,b,t]
//   vq[j][4] LDS staging (R10-verified); per j: 1 broadcast b128 + 2 coalesced b32 + 8 fma.
__global__ __launch_bounds__(256, 4) void stageC_kernel(const float* __restrict__ Vt,
                                                        const float* __restrict__ CyC,
                                                        float* __restrict__ out,
                                                        float* __restrict__ partial) {
  __shared__ float vq[2048];  // [j][4] = {b0t0, b1t0, b0t1, b1t1}
  int t0 = blockIdx.x << 1;
  int tid = threadIdx.x;
#pragma unroll
  for (int r = 0; r < 2; ++r) {
    int jj = tid + (r << 8);
    const float* base = Vt + (jj << 10);
    vq[(jj << 2) + 0] = base[t0];
    vq[(jj << 2) + 1] = base[512 + t0];
    vq[(jj << 2) + 2] = base[t0 + 1];
    vq[(jj << 2) + 3] = base[512 + t0 + 1];
  }
  __syncthreads();
  int l0 = tid;
  int l1 = tid + 256;
  float a00 = 0.f, a01 = 0.f, a10 = 0.f, a11 = 0.f;  // l0: (b0t0,b1t0,b0t1,b1t1)
  float b00 = 0.f, b01 = 0.f, b10 = 0.f, b11 = 0.f;  // l1
#pragma unroll 8
  for (int j = 0; j < 512; ++j) {
    float c0 = CyC[(j << 9) + l0];
    float c1 = CyC[(j << 9) + l1];
    float4 v = *(const float4*)&vq[j << 2];
    a00 = fmaf(c0, v.x, a00); a01 = fmaf(c0, v.y, a01);
    a10 = fmaf(c0, v.z, a10); a11 = fmaf(c0, v.w, a11);
    b00 = fmaf(c1, v.x, b00); b01 = fmaf(c1, v.y, b01);
    b10 = fmaf(c1, v.z, b10); b11 = fmaf(c1, v.w, b11);
  }
  float p00 = a00 / 3.0f, p01 = a01 / 3.0f, p10 = a10 / 3.0f, p11 = a11 / 3.0f;
  float r00 = b00 / 3.0f, r01 = b01 / 3.0f, r10 = b10 / 3.0f, r11 = b11 / 3.0f;
  out[(t0 << 9) + l0] = p00;
  out[((t0 + 1) << 9) + l0] = p10;
  out[HALF_N + (t0 << 9) + l0] = p01;
  out[HALF_N + ((t0 + 1) << 9) + l0] = p11;
  out[(t0 << 9) + l1] = r00;
  out[((t0 + 1) << 9) + l1] = r10;
  out[HALF_N + (t0 << 9) + l1] = r01;
  out[HALF_N + ((t0 + 1) << 9) + l1] = r11;
  // stats: per-thread partials over 8 outputs per batch-half? (4 per b), then reduce
  float s0 = (p00 + p10) + (r00 + r10);
  float q0 = fmaf(p00, p00, p10 * p10) + fmaf(r00, r00, r10 * r10);
  float s1 = (p01 + p11) + (r01 + r11);
  float q1 = fmaf(p01, p01, p11 * p11) + fmaf(r01, r01, r11 * r11);
  for (int off = 32; off > 0; off >>= 1) {
    s0 += __shfl_down(s0, off);
    q0 += __shfl_down(q0, off);
    s1 += __shfl_down(s1, off);
    q1 += __shfl_down(q1, off);
  }
  __shared__ float red[4][4];
  int wave = tid >> 6;
  if ((tid & 63) == 0) {
    red[wave][0] = s0; red[wave][1] = q0; red[wave][2] = s1; red[wave][3] = q1;
  }
  __syncthreads();
  if (tid == 0) {
    float c0 = 0.f, c1 = 0.f, c2 = 0.f, c3 = 0.f;
    for (int wv = 0; wv < 4; ++wv) {
      c0 += red[wv][0]; c1 += red[wv][1]; c2 += red[wv][2]; c3 += red[wv][3];
    }
    partial[blockIdx.x * 4 + 0] = c0;
    partial[blockIdx.x * 4 + 1] = c1;
    partial[blockIdx.x * 4 + 2] = c2;
    partial[blockIdx.x * 4 + 3] = c3;
  }
}

// Fused stats + noise: redundant partial reduce (256 quads) -> (std0,std1), then threefry noise.
// element i -> threefry2x32(key=(0,42), ctr=(0,i)), bits = o0^o1
__global__ __launch_bounds__(256) void noise_kernel(float* __restrict__ out,
                                                    const float* __restrict__ partial) {
  int tid = threadIdx.x;
  const float4* pq = (const float4*)partial;  // 256 quads {s0,q0,s1,q1}
  float4 pa = pq[tid];
  float s0 = pa.x, q0 = pa.y, s1 = pa.z, q1 = pa.w;
  for (int off = 32; off > 0; off >>= 1) {
    s0 += __shfl_down(s0, off);
    q0 += __shfl_down(q0, off);
    s1 += __shfl_down(s1, off);
    q1 += __shfl_down(q1, off);
  }
  __shared__ float red[4][4];
  int wave = tid >> 6;
  if ((tid & 63) == 0) {
    red[wave][0] = s0; red[wave][1] = q0; red[wave][2] = s1; red[wave][3] = q1;
  }
  __syncthreads();
  float S = red[0][0] + red[1][0] + red[2][0] + red[3][0];
  float Q = red[0][1] + red[1][1] + red[2][1] + red[3][1];
  float S2 = red[0][2] + red[1][2] + red[2][2] + red[3][2];
  float Q2 = red[0][3] + red[1][3] + red[2][3] + red[3][3];
  const float invN = 1.0f / 262144.0f;
  float m0 = S * invN, m1 = S2 * invN;
  float std0 = __fsqrt_rn(fmaxf(Q * invN - m0 * m0, 0.0f));
  float std1 = __fsqrt_rn(fmaxf(Q2 * invN - m1 * m1, 0.0f));

  int i = blockIdx.x * 256 + tid;  // < 524288
  uint32_t x0 = 0u;
  uint32_t x1 = (uint32_t)i;
  const uint32_t k0 = 0u, k1 = 42u;
  const uint32_t k2 = k0 ^ k1 ^ 0x1BD11BDAu;
  x0 += k0; x1 += k1;
#define QR(r) x0 += x1; x1 = rotl32(x1, r); x1 ^= x0;
  QR(13) QR(15) QR(26) QR(6)
  x0 += k1; x1 += k2 + 1u;
  QR(17) QR(29) QR(16) QR(24)
  x0 += k2; x1 += k0 + 2u;
  QR(13) QR(15) QR(26) QR(6)
  x0 += k0; x1 += k1 + 3u;
  QR(17) QR(29) QR(16) QR(24)
  x0 += k1; x1 += k2 + 4u;
  QR(13) QR(15) QR(26) QR(6)
  x0 += k2; x1 += k0 + 5u;
#undef QR
  uint32_t bits = x0 ^ x1;
  const float lo = __uint_as_float(0xBF7FFFFFu);  // nextafter(-1,0)
  float f = __uint_as_float((bits >> 9) | 0x3F800000u) - 1.0f;
  float u = fmaxf(lo, __fadd_rn(__fmul_rn(f, 2.0f), lo));
  const float sqrt2 = 1.41421356237309515f;
  out[i] += (i < HALF_N ? std0 : std1) * (sqrt2 * erfinv_xla(u));
}

extern "C" void kernel_launch(void* const* d_in, const int* in_sizes, int n_in,
                              void* d_out, int out_size, void* d_ws, size_t ws_size,
                              hipStream_t stream) {
  const float* x = (const float*)d_in[0];
  float* ws = (float*)d_ws;
  float* Vt      = ws;
  float* CyC     = ws + 524288;
  float* partial = ws + 786432;
  float* out = (float*)d_out;

  stageB_kernel<<<512, 256, 0, stream>>>(x, Vt, CyC);
  stageC_kernel<<<256, 256, 0, stream>>>(Vt, CyC, out, partial);
  noise_kernel<<<2048, 256, 0, stream>>>(out, partial);
}

// Round 5
// 135.446 us; speedup vs baseline: 1.5679x; 1.0092x over previous
//
#include <hip/hip_runtime.h>
#include <stdint.h>
#include <math.h>

// PhysicsForwardModel: B=2, Nz=Nx=128, Ly=Lx=512.
// out[b,t,l] = (1/3) * sum_j Cy[j,l] * sum_k cos(F[k,j]*t) * a[k] * (Cy[:,:128] x[b] Cy[:,128:256]^T)[k,j]
//              + std_b * N(0,1)  (JAX threefry key=42, partitionable counters, XLA erfinv)
// R14: R13 showed LDS broadcasts are NOT the bottleneck (halving them changed nothing) --
//      the cost is VALU/trans issue + idle waves (phase imbalance, low occupancy, scattered vq).
//  - B1 (grid 512x256): phases A/A2/B + CyC fold; writes fs/msf to global (3 MB).
//  - B2 (grid 1024x256 = (j, t-half)): stages fs/msf into LDS coalesced, runs R10's exact
//    per-t phase-C chain at 4 blocks/CU (16 waves/CU, no phase imbalance). Writes VtT[b][t][j]
//    (scattered dword stores, 2 MB total -- cheap) so stageC reads coalesced rows.
//  - stageC (grid 512x256, R10 block/partial scheme): vq[j][4] staged from VtT rows
//    (coalesced), c from CyC table (bit-identical values; fmaf-from-0 == mul exactly).
//  - noise: R1-verified 512-quad reducer.
// All per-output accumulation chains bit-identical to the 128.9us R10 kernel.

#define HALF_N 262144  // 512*512 per-batch elements
#define PI_F 3.14159274101257324f

// ws layout (floats):
//   VtT     [0       .. 524288)   [b][t][j]
//   CyC     [524288  .. 786432)   [j][l] stageC coefficient (scale folded)
//   fsg     [786432  .. 1048576)  [j][k] = F[k,j]
//   msfg    [1048576 .. 1572864)  [j][k][2] = {m_b0, m_b1}
//   partial [1572864 .. 1574912)  512 blocks x {s0,q0,s1,q1}

__device__ __forceinline__ uint32_t rotl32(uint32_t v, int r) {
  return (v << r) | (v >> (32 - r));
}

// XLA ErfInv32 (Giles) -- matches reference's lax.erf_inv
__device__ __forceinline__ float erfinv_xla(float x) {
  float w = -log1pf(__fmul_rn(-x, x));
  float p;
  if (w < 5.0f) {
    w = w - 2.5f;
    p = 2.81022636e-08f;
    p = fmaf(p, w, 3.43273939e-07f);
    p = fmaf(p, w, -3.5233877e-06f);
    p = fmaf(p, w, -4.39150654e-06f);
    p = fmaf(p, w, 0.00021858087f);
    p = fmaf(p, w, -0.00125372503f);
    p = fmaf(p, w, -0.00417768164f);
    p = fmaf(p, w, 0.246640727f);
    p = fmaf(p, w, 1.50140941f);
  } else {
    w = __fsqrt_rn(w) - 3.0f;
    p = -0.000200214257f;
    p = fmaf(p, w, 0.000100950558f);
    p = fmaf(p, w, 0.00134934322f);
    p = fmaf(p, w, -0.00367342844f);
    p = fmaf(p, w, 0.00573950773f);
    p = fmaf(p, w, -0.0076224613f);
    p = fmaf(p, w, 0.00943887047f);
    p = fmaf(p, w, 1.00167406f);
    p = fmaf(p, w, 2.83297682f);
  }
  return p * x;
}

// Cy[k,n] = sc(k) * 2 * cos(pi*(2n+1)*k/1024), with n2p1 = (float)(2n+1) exact
__device__ __forceinline__ float cy_elem(float n2p1, float kf, float sc) {
  float t1 = __fmul_rn(PI_F, n2p1);
  float arg = __fmul_rn(t1, kf) * (1.0f / 1024.0f);
  return __fmul_rn(sc, __fmul_rn(2.0f, __cosf(arg)));
}

// B1, block = j (grid 512, 256 threads): phases A/A2/B + CyC fold.
__global__ __launch_bounds__(256, 4) void stageB1_kernel(const float* __restrict__ x,
                                                         float* __restrict__ fsg,
                                                         float2* __restrict__ msfg,
                                                         float* __restrict__ CyC) {
  __shared__ float cyl[128];
  __shared__ float us[256];
  int j = blockIdx.x;
  int tid = threadIdx.x;
  float jf = (float)j;
  // CyC[j][l] for l = tid and tid+256. Bit-identical to R10 stageC's on-the-fly coefficients.
  if (j == 0) {
    float c = __fmul_rn(1.0f / __fsqrt_rn(2048.0f), 2.0f);
    CyC[tid] = c;
    CyC[tid + 256] = c;
  } else {
    float t1a = __fmul_rn(PI_F, (float)(2 * tid + 1));
    float t1b = __fmul_rn(PI_F, (float)(2 * (tid + 256) + 1));
    CyC[(j << 9) + tid] = __fmul_rn(0.0625f, __cosf(__fmul_rn(t1a, jf) * (1.0f / 1024.0f)));
    CyC[(j << 9) + tid + 256] = __fmul_rn(0.0625f, __cosf(__fmul_rn(t1b, jf) * (1.0f / 1024.0f)));
  }
  if (tid < 128) {
    float scj = (j == 0) ? (1.0f / __fsqrt_rn(2048.0f)) : 0.03125f;
    cyl[tid] = cy_elem((float)(2 * (128 + tid) + 1), jf, scj);
  }
  __syncthreads();
  {
    int b = tid >> 7, i = tid & 127;
    const float* xr = x + (b * 128 + i) * 128;
    float accA = 0.0f, accB = 0.0f;
    for (int jj = 0; jj < 128; jj += 8) {
      float4 xa = *(const float4*)&xr[jj];
      float4 xb = *(const float4*)&xr[jj + 4];
      float4 ca = *(const float4*)&cyl[jj];
      float4 cb = *(const float4*)&cyl[jj + 4];
      accA = fmaf(xa.x, ca.x, accA); accB = fmaf(xa.y, ca.y, accB);
      accA = fmaf(xa.z, ca.z, accA); accB = fmaf(xa.w, ca.w, accB);
      accA = fmaf(xb.x, cb.x, accA); accB = fmaf(xb.y, cb.y, accB);
      accA = fmaf(xb.z, cb.z, accA); accB = fmaf(xb.w, cb.w, accB);
    }
    us[tid] = accA + accB;
  }
  __syncthreads();
  for (int kk = 0; kk < 2; ++kk) {
    int k = tid + (kk << 8);
    float kf = (float)k;
    float sc = (k == 0) ? (1.0f / __fsqrt_rn(2048.0f)) : 0.03125f;
    float a = cy_elem(1.0f, kf, sc);  // i=0: a[k] = Cy[k,0]
    float acc0 = __fmul_rn(a, us[0]);
    float acc1 = __fmul_rn(a, us[128]);
    float accA0 = 0.f, accA1 = 0.f;
    {
      float c1 = cy_elem(3.0f, kf, sc);
      float c2 = cy_elem(5.0f, kf, sc);
      float c3 = cy_elem(7.0f, kf, sc);
      acc0 = fmaf(c1, us[1], acc0);   acc1 = fmaf(c1, us[129], acc1);
      accA0 = fmaf(c2, us[2], accA0); accA1 = fmaf(c2, us[130], accA1);
      acc0 = fmaf(c3, us[3], acc0);   acc1 = fmaf(c3, us[131], acc1);
    }
    for (int i = 4; i < 128; i += 4) {
      float b0 = (float)(2 * i + 1);
      float c0 = cy_elem(b0, kf, sc);
      float c1 = cy_elem(__fadd_rn(b0, 2.0f), kf, sc);
      float c2 = cy_elem(__fadd_rn(b0, 4.0f), kf, sc);
      float c3 = cy_elem(__fadd_rn(b0, 6.0f), kf, sc);
      float4 u0 = *(const float4*)&us[i];
      float4 u1 = *(const float4*)&us[128 + i];
      acc0 = fmaf(c0, u0.x, acc0);   acc1 = fmaf(c0, u1.x, acc1);
      accA0 = fmaf(c1, u0.y, accA0); accA1 = fmaf(c1, u1.y, accA1);
      acc0 = fmaf(c2, u0.z, acc0);   acc1 = fmaf(c2, u1.z, acc1);
      accA0 = fmaf(c3, u0.w, accA0); accA1 = fmaf(c3, u1.w, accA1);
    }
    acc0 += accA0;
    acc1 += accA1;
    const float w0 = PI_F / 512.0f;  // exact pow2 scale of pi_f
    float ky = __fmul_rn(kf, w0);
    float kx = __fmul_rn(jf, w0);
    fsg[(j << 9) + k] = __fsqrt_rn(__fadd_rn(__fmul_rn(ky, ky), __fmul_rn(kx, kx)));
    msfg[(j << 9) + k] = make_float2(__fmul_rn(a, acc0), __fmul_rn(a, acc1));
  }
}

// B2, block = (j, t-half) (grid 1024, 256 threads), thread owns one t.
//   VtT[b][t][j] = sum_k cos(fs[k]*t) * msf[2k+b] -- R10's exact per-t chain.
__global__ __launch_bounds__(256, 4) void stageB2_kernel(const float* __restrict__ fsg,
                                                         const float* __restrict__ msfg,
                                                         float* __restrict__ VtT) {
  __shared__ float fs[512];
  __shared__ float msf[1024];
  int j = blockIdx.x >> 1;
  int th = blockIdx.x & 1;
  int tid = threadIdx.x;
  // coalesced stage: fs (2 dwords), msf (4 dwords)
  fs[tid] = fsg[(j << 9) + tid];
  fs[tid + 256] = fsg[(j << 9) + tid + 256];
  msf[tid] = msfg[(j << 10) + tid];
  msf[tid + 256] = msfg[(j << 10) + tid + 256];
  msf[tid + 512] = msfg[(j << 10) + tid + 512];
  msf[tid + 768] = msfg[(j << 10) + tid + 768];
  __syncthreads();
  int t = (th << 8) + tid;
  float tf = (float)t;
  float acc0 = 0.f, acc1 = 0.f, acc2 = 0.f, acc3 = 0.f;
  for (int k0 = 0; k0 < 512; k0 += 8) {
    float4 f0 = *(const float4*)&fs[k0];
    float4 f1 = *(const float4*)&fs[k0 + 4];
    float4 m0 = *(const float4*)&msf[2 * k0];
    float4 m1 = *(const float4*)&msf[2 * k0 + 4];
    float4 m2 = *(const float4*)&msf[2 * k0 + 8];
    float4 m3 = *(const float4*)&msf[2 * k0 + 12];
    float ph0 = __cosf(__fmul_rn(f0.x, tf));  // arg bit-matches ref's f32 F*t
    float ph1 = __cosf(__fmul_rn(f0.y, tf));
    float ph2 = __cosf(__fmul_rn(f0.z, tf));
    float ph3 = __cosf(__fmul_rn(f0.w, tf));
    float ph4 = __cosf(__fmul_rn(f1.x, tf));
    float ph5 = __cosf(__fmul_rn(f1.y, tf));
    float ph6 = __cosf(__fmul_rn(f1.z, tf));
    float ph7 = __cosf(__fmul_rn(f1.w, tf));
    acc0 = fmaf(ph0, m0.x, acc0); acc1 = fmaf(ph0, m0.y, acc1);
    acc2 = fmaf(ph1, m0.z, acc2); acc3 = fmaf(ph1, m0.w, acc3);
    acc0 = fmaf(ph2, m1.x, acc0); acc1 = fmaf(ph2, m1.y, acc1);
    acc2 = fmaf(ph3, m1.z, acc2); acc3 = fmaf(ph3, m1.w, acc3);
    acc0 = fmaf(ph4, m2.x, acc0); acc1 = fmaf(ph4, m2.y, acc1);
    acc2 = fmaf(ph5, m2.z, acc2); acc3 = fmaf(ph5, m2.w, acc3);
    acc0 = fmaf(ph6, m3.x, acc0); acc1 = fmaf(ph6, m3.y, acc1);
    acc2 = fmaf(ph7, m3.z, acc2); acc3 = fmaf(ph7, m3.w, acc3);
  }
  VtT[(t << 9) + j] = acc0 + acc2;               // b0
  VtT[HALF_N + (t << 9) + j] = acc1 + acc3;      // b1
}

// stageC: block = (t-pair, l-half) (grid 512, 256 threads), lane = l. R10 block/partial scheme.
//   out[b,t,l] = (1/3) * sum_j CyC[j,l] * VtT[b][t][j]
//   vq[j][4] staged from VtT rows (coalesced); per j: 1 coalesced c-load + b128 + 4 fma.
__global__ __launch_bounds__(256, 4) void stageC_kernel(const float* __restrict__ VtT,
                                                        const float* __restrict__ CyC,
                                                        float* __restrict__ out,
                                                        float* __restrict__ partial) {
  __shared__ float vq[2048];  // [j][4] = {b0t0, b1t0, b0t1, b1t1}
  int tpair = blockIdx.x >> 1;
  int lhalf = blockIdx.x & 1;
  int t0 = tpair << 1;
  int tid = threadIdx.x;
#pragma unroll
  for (int s = 0; s < 4; ++s) {
    int b = s & 1, dt = s >> 1;
    const float* row = VtT + b * HALF_N + ((t0 + dt) << 9);
    vq[(tid << 2) + s] = row[tid];
    vq[((tid + 256) << 2) + s] = row[tid + 256];
  }
  __syncthreads();
  int l = (lhalf << 8) + tid;
  float a00 = 0.f, a01 = 0.f, a10 = 0.f, a11 = 0.f;
#pragma unroll 8
  for (int j = 0; j < 512; ++j) {
    float c = CyC[(j << 9) + l];
    float4 v = *(const float4*)&vq[j << 2];
    a00 = fmaf(c, v.x, a00);
    a01 = fmaf(c, v.y, a01);
    a10 = fmaf(c, v.z, a10);
    a11 = fmaf(c, v.w, a11);
  }
  float p00 = a00 / 3.0f, p01 = a01 / 3.0f, p10 = a10 / 3.0f, p11 = a11 / 3.0f;
  out[(t0 << 9) + l] = p00;
  out[((t0 + 1) << 9) + l] = p10;
  out[HALF_N + (t0 << 9) + l] = p01;
  out[HALF_N + ((t0 + 1) << 9) + l] = p11;
  float s0 = p00 + p10, q0 = fmaf(p00, p00, p10 * p10);
  float s1 = p01 + p11, q1 = fmaf(p01, p01, p11 * p11);
  for (int off = 32; off > 0; off >>= 1) {
    s0 += __shfl_down(s0, off);
    q0 += __shfl_down(q0, off);
    s1 += __shfl_down(s1, off);
    q1 += __shfl_down(q1, off);
  }
  __shared__ float red[4][4];
  int wave = tid >> 6;
  if ((tid & 63) == 0) {
    red[wave][0] = s0; red[wave][1] = q0; red[wave][2] = s1; red[wave][3] = q1;
  }
  __syncthreads();
  if (tid == 0) {
    float c0 = 0.f, c1 = 0.f, c2 = 0.f, c3 = 0.f;
    for (int wv = 0; wv < 4; ++wv) {
      c0 += red[wv][0]; c1 += red[wv][1]; c2 += red[wv][2]; c3 += red[wv][3];
    }
    partial[blockIdx.x * 4 + 0] = c0;
    partial[blockIdx.x * 4 + 1] = c1;
    partial[blockIdx.x * 4 + 2] = c2;
    partial[blockIdx.x * 4 + 3] = c3;
  }
}

// Fused stats + noise: redundant partial reduce (512 quads) -> (std0,std1), then threefry noise.
// element i -> threefry2x32(key=(0,42), ctr=(0,i)), bits = o0^o1
__global__ __launch_bounds__(256) void noise_kernel(float* __restrict__ out,
                                                    const float* __restrict__ partial) {
  int tid = threadIdx.x;
  const float4* pq = (const float4*)partial;  // 512 quads {s0,q0,s1,q1}
  float4 pa = pq[tid];
  float4 pb = pq[tid + 256];
  float s0 = pa.x + pb.x, q0 = pa.y + pb.y, s1 = pa.z + pb.z, q1 = pa.w + pb.w;
  for (int off = 32; off > 0; off >>= 1) {
    s0 += __shfl_down(s0, off);
    q0 += __shfl_down(q0, off);
    s1 += __shfl_down(s1, off);
    q1 += __shfl_down(q1, off);
  }
  __shared__ float red[4][4];
  int wave = tid >> 6;
  if ((tid & 63) == 0) {
    red[wave][0] = s0; red[wave][1] = q0; red[wave][2] = s1; red[wave][3] = q1;
  }
  __syncthreads();
  float S = red[0][0] + red[1][0] + red[2][0] + red[3][0];
  float Q = red[0][1] + red[1][1] + red[2][1] + red[3][1];
  float S2 = red[0][2] + red[1][2] + red[2][2] + red[3][2];
  float Q2 = red[0][3] + red[1][3] + red[2][3] + red[3][3];
  const float invN = 1.0f / 262144.0f;
  float m0 = S * invN, m1 = S2 * invN;
  float std0 = __fsqrt_rn(fmaxf(Q * invN - m0 * m0, 0.0f));
  float std1 = __fsqrt_rn(fmaxf(Q2 * invN - m1 * m1, 0.0f));

  int i = blockIdx.x * 256 + tid;  // < 524288
  uint32_t x0 = 0u;
  uint32_t x1 = (uint32_t)i;
  const uint32_t k0 = 0u, k1 = 42u;
  const uint32_t k2 = k0 ^ k1 ^ 0x1BD11BDAu;
  x0 += k0; x1 += k1;
#define QR(r) x0 += x1; x1 = rotl32(x1, r); x1 ^= x0;
  QR(13) QR(15) QR(26) QR(6)
  x0 += k1; x1 += k2 + 1u;
  QR(17) QR(29) QR(16) QR(24)
  x0 += k2; x1 += k0 + 2u;
  QR(13) QR(15) QR(26) QR(6)
  x0 += k0; x1 += k1 + 3u;
  QR(17) QR(29) QR(16) QR(24)
  x0 += k1; x1 += k2 + 4u;
  QR(13) QR(15) QR(26) QR(6)
  x0 += k2; x1 += k0 + 5u;
#undef QR
  uint32_t bits = x0 ^ x1;
  const float lo = __uint_as_float(0xBF7FFFFFu);  // nextafter(-1,0)
  float f = __uint_as_float((bits >> 9) | 0x3F800000u) - 1.0f;
  float u = fmaxf(lo, __fadd_rn(__fmul_rn(f, 2.0f), lo));
  const float sqrt2 = 1.41421356237309515f;
  out[i] += (i < HALF_N ? std0 : std1) * (sqrt2 * erfinv_xla(u));
}

extern "C" void kernel_launch(void* const* d_in, const int* in_sizes, int n_in,
                              void* d_out, int out_size, void* d_ws, size_t ws_size,
                              hipStream_t stream) {
  const float* x = (const float*)d_in[0];
  float* ws = (float*)d_ws;
  float* VtT     = ws;
  float* CyC     = ws + 524288;
  float* fsg     = ws + 786432;
  float* msfg    = ws + 1048576;
  float* partial = ws + 1572864;
  float* out = (float*)d_out;

  stageB1_kernel<<<512, 256, 0, stream>>>(x, fsg, (float2*)msfg, CyC);
  stageB2_kernel<<<1024, 256, 0, stream>>>(fsg, msfg, VtT);
  stageC_kernel<<<512, 256, 0, stream>>>(VtT, CyC, out, partial);
  noise_kernel<<<2048, 256, 0, stream>>>(out, partial);
}

// Round 6
// 131.891 us; speedup vs baseline: 1.6102x; 1.0270x over previous
//
#include <hip/hip_runtime.h>
#include <stdint.h>
#include <math.h>

// PhysicsForwardModel: B=2, Nz=Nx=128, Ly=Lx=512.
// out[b,t,l] = (1/3) * sum_j Cy[j,l] * sum_k cos(F[k,j]*t) * a[k] * (Cy[:,:128] x[b] Cy[:,128:256]^T)[k,j]
//              + std_b * N(0,1)  (JAX threefry key=42, partitionable counters, XLA erfinv)
// R15: back to the verified R10 structure (R11-R14 all regressed: uniform VMEM, table
//      streaming, LDS-halving, and kernel-splitting each attacked a non-bottleneck).
//      ONE isolated change vs the 128.0us R1 kernel: stageC's 512 per-thread __cosf
//      coefficients come from a CyC[j][l] table folded into stageB (1 extra cos + 1 store
//      per stageB thread, issued in phase-A's idle slots). Coefficient values bit-identical;
//      fmaf(c,v,0)==mul bitwise -> out bit-identical. stageB phase A2/B/C byte-identical to R1.

#define HALF_N 262144  // 512*512 per-batch elements
#define PI_F 3.14159274101257324f

// ws layout (floats): Vt [0..524288) [j][b][t]; CyC [524288..786432) [j][l];
//                     partial [786432..788480)

__device__ __forceinline__ uint32_t rotl32(uint32_t v, int r) {
  return (v << r) | (v >> (32 - r));
}

// XLA ErfInv32 (Giles) -- matches reference's lax.erf_inv
__device__ __forceinline__ float erfinv_xla(float x) {
  float w = -log1pf(__fmul_rn(-x, x));
  float p;
  if (w < 5.0f) {
    w = w - 2.5f;
    p = 2.81022636e-08f;
    p = fmaf(p, w, 3.43273939e-07f);
    p = fmaf(p, w, -3.5233877e-06f);
    p = fmaf(p, w, -4.39150654e-06f);
    p = fmaf(p, w, 0.00021858087f);
    p = fmaf(p, w, -0.00125372503f);
    p = fmaf(p, w, -0.00417768164f);
    p = fmaf(p, w, 0.246640727f);
    p = fmaf(p, w, 1.50140941f);
  } else {
    w = __fsqrt_rn(w) - 3.0f;
    p = -0.000200214257f;
    p = fmaf(p, w, 0.000100950558f);
    p = fmaf(p, w, 0.00134934322f);
    p = fmaf(p, w, -0.00367342844f);
    p = fmaf(p, w, 0.00573950773f);
    p = fmaf(p, w, -0.0076224613f);
    p = fmaf(p, w, 0.00943887047f);
    p = fmaf(p, w, 1.00167406f);
    p = fmaf(p, w, 2.83297682f);
  }
  return p * x;
}

// Cy[k,n] = sc(k) * 2 * cos(pi*(2n+1)*k/1024), with n2p1 = (float)(2n+1) exact
__device__ __forceinline__ float cy_elem(float n2p1, float kf, float sc) {
  float t1 = __fmul_rn(PI_F, n2p1);
  float arg = __fmul_rn(t1, kf) * (1.0f / 1024.0f);
  return __fmul_rn(sc, __fmul_rn(2.0f, __cosf(arg)));
}

// fusedB, block = j (grid 512, 512 threads):
//   CyC fold:     CyC[j][tid] = stageC coefficient (bit-identical to R1 stageC's on-the-fly)
//   A  (tid<128): cyl[jj] = Cy[j,128+jj]
//   A2 (tid<256): us[b*128+i] = sum_jj x[b,i,jj]*cyl[jj]
//   B  (lane=k):  msf[2k+b] = a[k] * sum_i Cy[k,i]*us[b,i]; fs[k] = F[k,j]
//   C  (lane=t):  Vt[j,b,t] = sum_k cos(fs[k]*t) * msf[2k+b]
__global__ __launch_bounds__(512, 4) void stageB_kernel(const float* __restrict__ x,
                                                        float* __restrict__ Vt,
                                                        float* __restrict__ CyC) {
  __shared__ float cyl[128];
  __shared__ float us[256];
  __shared__ float fs[512];
  __shared__ float msf[1024];
  int j = blockIdx.x;
  int tid = threadIdx.x;
  float jf = (float)j;
  // CyC[j][l], l = tid. Bit-identical to R1 stageC's coefficients:
  //   j==0: (1/sqrt(2048))*2 ; j>=1: 0.0625*__cosf(fmul(fmul(PI,(2l+1)), j) * (1/1024))
  {
    float c;
    if (j == 0) {
      c = __fmul_rn(1.0f / __fsqrt_rn(2048.0f), 2.0f);
    } else {
      float t1 = __fmul_rn(PI_F, (float)(2 * tid + 1));
      c = __fmul_rn(0.0625f, __cosf(__fmul_rn(t1, jf) * (1.0f / 1024.0f)));
    }
    CyC[(j << 9) + tid] = c;
  }
  if (tid < 128) {
    float scj = (j == 0) ? (1.0f / __fsqrt_rn(2048.0f)) : 0.03125f;
    cyl[tid] = cy_elem((float)(2 * (128 + tid) + 1), jf, scj);
  }
  __syncthreads();
  if (tid < 256) {
    int b = tid >> 7, i = tid & 127;
    const float* xr = x + (b * 128 + i) * 128;
    float accA = 0.0f, accB = 0.0f;
    for (int jj = 0; jj < 128; jj += 8) {
      float4 xa = *(const float4*)&xr[jj];
      float4 xb = *(const float4*)&xr[jj + 4];
      float4 ca = *(const float4*)&cyl[jj];
      float4 cb = *(const float4*)&cyl[jj + 4];
      accA = fmaf(xa.x, ca.x, accA); accB = fmaf(xa.y, ca.y, accB);
      accA = fmaf(xa.z, ca.z, accA); accB = fmaf(xa.w, ca.w, accB);
      accA = fmaf(xb.x, cb.x, accA); accB = fmaf(xb.y, cb.y, accB);
      accA = fmaf(xb.z, cb.z, accA); accB = fmaf(xb.w, cb.w, accB);
    }
    us[tid] = accA + accB;
  }
  __syncthreads();
  {
    float kf = (float)tid;
    float sc = (tid == 0) ? (1.0f / __fsqrt_rn(2048.0f)) : 0.03125f;
    float a = cy_elem(1.0f, kf, sc);  // i=0: a[k] = Cy[k,0]
    float acc0 = __fmul_rn(a, us[0]);
    float acc1 = __fmul_rn(a, us[128]);
    // i = 1..3 singles, then aligned batches of 4
    float accA0 = 0.f, accA1 = 0.f;
    {
      float c1 = cy_elem(3.0f, kf, sc);
      float c2 = cy_elem(5.0f, kf, sc);
      float c3 = cy_elem(7.0f, kf, sc);
      acc0 = fmaf(c1, us[1], acc0);   acc1 = fmaf(c1, us[129], acc1);
      accA0 = fmaf(c2, us[2], accA0); accA1 = fmaf(c2, us[130], accA1);
      acc0 = fmaf(c3, us[3], acc0);   acc1 = fmaf(c3, us[131], acc1);
    }
    for (int i = 4; i < 128; i += 4) {
      float b0 = (float)(2 * i + 1);
      float c0 = cy_elem(b0, kf, sc);
      float c1 = cy_elem(__fadd_rn(b0, 2.0f), kf, sc);
      float c2 = cy_elem(__fadd_rn(b0, 4.0f), kf, sc);
      float c3 = cy_elem(__fadd_rn(b0, 6.0f), kf, sc);
      float4 u0 = *(const float4*)&us[i];
      float4 u1 = *(const float4*)&us[128 + i];
      acc0 = fmaf(c0, u0.x, acc0);   acc1 = fmaf(c0, u1.x, acc1);
      accA0 = fmaf(c1, u0.y, accA0); accA1 = fmaf(c1, u1.y, accA1);
      acc0 = fmaf(c2, u0.z, acc0);   acc1 = fmaf(c2, u1.z, acc1);
      accA0 = fmaf(c3, u0.w, accA0); accA1 = fmaf(c3, u1.w, accA1);
    }
    acc0 += accA0;
    acc1 += accA1;
    const float w0 = PI_F / 512.0f;  // exact pow2 scale of pi_f
    float ky = __fmul_rn(kf, w0);
    float kx = __fmul_rn(jf, w0);
    fs[tid] = __fsqrt_rn(__fadd_rn(__fmul_rn(ky, ky), __fmul_rn(kx, kx)));
    msf[2 * tid] = __fmul_rn(a, acc0);
    msf[2 * tid + 1] = __fmul_rn(a, acc1);
  }
  __syncthreads();
  float tf = (float)tid;
  float acc0 = 0.f, acc1 = 0.f, acc2 = 0.f, acc3 = 0.f;
  for (int k0 = 0; k0 < 512; k0 += 8) {
    float4 f0 = *(const float4*)&fs[k0];
    float4 f1 = *(const float4*)&fs[k0 + 4];
    float4 m0 = *(const float4*)&msf[2 * k0];
    float4 m1 = *(const float4*)&msf[2 * k0 + 4];
    float4 m2 = *(const float4*)&msf[2 * k0 + 8];
    float4 m3 = *(const float4*)&msf[2 * k0 + 12];
    float ph0 = __cosf(__fmul_rn(f0.x, tf));  // arg bit-matches ref's f32 F*t
    float ph1 = __cosf(__fmul_rn(f0.y, tf));
    float ph2 = __cosf(__fmul_rn(f0.z, tf));
    float ph3 = __cosf(__fmul_rn(f0.w, tf));
    float ph4 = __cosf(__fmul_rn(f1.x, tf));
    float ph5 = __cosf(__fmul_rn(f1.y, tf));
    float ph6 = __cosf(__fmul_rn(f1.z, tf));
    float ph7 = __cosf(__fmul_rn(f1.w, tf));
    acc0 = fmaf(ph0, m0.x, acc0); acc1 = fmaf(ph0, m0.y, acc1);
    acc2 = fmaf(ph1, m0.z, acc2); acc3 = fmaf(ph1, m0.w, acc3);
    acc0 = fmaf(ph2, m1.x, acc0); acc1 = fmaf(ph2, m1.y, acc1);
    acc2 = fmaf(ph3, m1.z, acc2); acc3 = fmaf(ph3, m1.w, acc3);
    acc0 = fmaf(ph4, m2.x, acc0); acc1 = fmaf(ph4, m2.y, acc1);
    acc2 = fmaf(ph5, m2.z, acc2); acc3 = fmaf(ph5, m2.w, acc3);
    acc0 = fmaf(ph6, m3.x, acc0); acc1 = fmaf(ph6, m3.y, acc1);
    acc2 = fmaf(ph7, m3.z, acc2); acc3 = fmaf(ph7, m3.w, acc3);
  }
  Vt[(j << 10) + tid] = acc0 + acc2;
  Vt[(j << 10) + 512 + tid] = acc1 + acc3;
}

// stageC: out[b,t,l] = (1/3) * sum_j CyC[j,l] * Vt[j,b,t].
// Identical to the R1 stageC except coefficients load from CyC (bit-identical values;
// fmaf(c,v,0) == c*v bitwise so all chains are bit-identical to R1's).
__global__ __launch_bounds__(256, 4) void stageC_kernel(const float* __restrict__ Vt,
                                                        const float* __restrict__ CyC,
                                                        float* __restrict__ out,
                                                        float* __restrict__ partial) {
  __shared__ float vq[2048];  // [j][4] = {b0t0, b1t0, b0t1, b1t1}
  int tpair = blockIdx.x >> 1;
  int lhalf = blockIdx.x & 1;
  int t0 = tpair << 1;
  int tid = threadIdx.x;
#pragma unroll
  for (int r = 0; r < 2; ++r) {
    int j = tid + (r << 8);
    const float* base = Vt + (j << 10);
    vq[(j << 2) + 0] = base[t0];
    vq[(j << 2) + 1] = base[512 + t0];
    vq[(j << 2) + 2] = base[t0 + 1];
    vq[(j << 2) + 3] = base[512 + t0 + 1];
  }
  __syncthreads();
  int l = (lhalf << 8) + tid;
  float a00 = 0.f, a01 = 0.f, a10 = 0.f, a11 = 0.f;
#pragma unroll 8
  for (int j = 0; j < 512; ++j) {
    float c = CyC[(j << 9) + l];
    float4 v = *(const float4*)&vq[j << 2];
    a00 = fmaf(c, v.x, a00);
    a01 = fmaf(c, v.y, a01);
    a10 = fmaf(c, v.z, a10);
    a11 = fmaf(c, v.w, a11);
  }
  float p00 = a00 / 3.0f, p01 = a01 / 3.0f, p10 = a10 / 3.0f, p11 = a11 / 3.0f;
  out[(t0 << 9) + l] = p00;
  out[((t0 + 1) << 9) + l] = p10;
  out[HALF_N + (t0 << 9) + l] = p01;
  out[HALF_N + ((t0 + 1) << 9) + l] = p11;
  float s0 = p00 + p10, q0 = fmaf(p00, p00, p10 * p10);
  float s1 = p01 + p11, q1 = fmaf(p01, p01, p11 * p11);
  for (int off = 32; off > 0; off >>= 1) {
    s0 += __shfl_down(s0, off);
    q0 += __shfl_down(q0, off);
    s1 += __shfl_down(s1, off);
    q1 += __shfl_down(q1, off);
  }
  __shared__ float red[4][4];
  int wave = tid >> 6;
  if ((tid & 63) == 0) {
    red[wave][0] = s0; red[wave][1] = q0; red[wave][2] = s1; red[wave][3] = q1;
  }
  __syncthreads();
  if (tid == 0) {
    float a0 = 0.f, a1 = 0.f, a2 = 0.f, a3 = 0.f;
    for (int wv = 0; wv < 4; ++wv) {
      a0 += red[wv][0]; a1 += red[wv][1]; a2 += red[wv][2]; a3 += red[wv][3];
    }
    partial[blockIdx.x * 4 + 0] = a0;
    partial[blockIdx.x * 4 + 1] = a1;
    partial[blockIdx.x * 4 + 2] = a2;
    partial[blockIdx.x * 4 + 3] = a3;
  }
}

// Fused stats + noise: redundant partial reduce (512 quads) -> (std0,std1), then threefry noise.
// element i -> threefry2x32(key=(0,42), ctr=(0,i)), bits = o0^o1
__global__ __launch_bounds__(256) void noise_kernel(float* __restrict__ out,
                                                    const float* __restrict__ partial) {
  int tid = threadIdx.x;
  const float4* pq = (const float4*)partial;  // 512 quads {s0,q0,s1,q1}
  float4 pa = pq[tid];
  float4 pb = pq[tid + 256];
  float s0 = pa.x + pb.x, q0 = pa.y + pb.y, s1 = pa.z + pb.z, q1 = pa.w + pb.w;
  for (int off = 32; off > 0; off >>= 1) {
    s0 += __shfl_down(s0, off);
    q0 += __shfl_down(q0, off);
    s1 += __shfl_down(s1, off);
    q1 += __shfl_down(q1, off);
  }
  __shared__ float red[4][4];
  int wave = tid >> 6;
  if ((tid & 63) == 0) {
    red[wave][0] = s0; red[wave][1] = q0; red[wave][2] = s1; red[wave][3] = q1;
  }
  __syncthreads();
  float S = red[0][0] + red[1][0] + red[2][0] + red[3][0];
  float Q = red[0][1] + red[1][1] + red[2][1] + red[3][1];
  float S2 = red[0][2] + red[1][2] + red[2][2] + red[3][2];
  float Q2 = red[0][3] + red[1][3] + red[2][3] + red[3][3];
  const float invN = 1.0f / 262144.0f;
  float m0 = S * invN, m1 = S2 * invN;
  float std0 = __fsqrt_rn(fmaxf(Q * invN - m0 * m0, 0.0f));
  float std1 = __fsqrt_rn(fmaxf(Q2 * invN - m1 * m1, 0.0f));

  int i = blockIdx.x * 256 + tid;  // < 524288
  uint32_t x0 = 0u;
  uint32_t x1 = (uint32_t)i;
  const uint32_t k0 = 0u, k1 = 42u;
  const uint32_t k2 = k0 ^ k1 ^ 0x1BD11BDAu;
  x0 += k0; x1 += k1;
#define QR(r) x0 += x1; x1 = rotl32(x1, r); x1 ^= x0;
  QR(13) QR(15) QR(26) QR(6)
  x0 += k1; x1 += k2 + 1u;
  QR(17) QR(29) QR(16) QR(24)
  x0 += k2; x1 += k0 + 2u;
  QR(13) QR(15) QR(26) QR(6)
  x0 += k0; x1 += k1 + 3u;
  QR(17) QR(29) QR(16) QR(24)
  x0 += k1; x1 += k2 + 4u;
  QR(13) QR(15) QR(26) QR(6)
  x0 += k2; x1 += k0 + 5u;
#undef QR
  uint32_t bits = x0 ^ x1;
  const float lo = __uint_as_float(0xBF7FFFFFu);  // nextafter(-1,0)
  float f = __uint_as_float((bits >> 9) | 0x3F800000u) - 1.0f;
  float u = fmaxf(lo, __fadd_rn(__fmul_rn(f, 2.0f), lo));
  const float sqrt2 = 1.41421356237309515f;
  out[i] += (i < HALF_N ? std0 : std1) * (sqrt2 * erfinv_xla(u));
}

extern "C" void kernel_launch(void* const* d_in, const int* in_sizes, int n_in,
                              void* d_out, int out_size, void* d_ws, size_t ws_size,
                              hipStream_t stream) {
  const float* x = (const float*)d_in[0];
  float* ws = (float*)d_ws;
  float* Vt      = ws;
  float* CyC     = ws + 524288;
  float* partial = ws + 786432;
  float* out = (float*)d_out;

  stageB_kernel<<<512, 512, 0, stream>>>(x, Vt, CyC);
  stageC_kernel<<<512, 256, 0, stream>>>(Vt, CyC, out, partial);
  noise_kernel<<<2048, 256, 0, stream>>>(out, partial);
}

// Round 7
// 131.473 us; speedup vs baseline: 1.6153x; 1.0032x over previous
//
#include <hip/hip_runtime.h>
#include <stdint.h>
#include <math.h>

// PhysicsForwardModel: B=2, Nz=Nx=128, Ly=Lx=512.
// out[b,t,l] = (1/3) * sum_j Cy[j,l] * sum_k cos(F[k,j]*t) * a[k] * (Cy[:,:128] x[b] Cy[:,128:256]^T)[k,j]
//              + std_b * N(0,1)  (JAX threefry key=42, partitionable counters, XLA erfinv)
// R16: stageB = R1's verified 41.3us kernel byte-for-byte (CyC experiment closed: table was
//      slightly WORSE than cos-recompute -- trans pipe is cheap, VMEM isn't).
//      stageC restructured for occupancy: block = t (grid 512 x 512 thr, launch_bounds(512,4)
//      -> 50% occ vs 25%), thread owns one (t,l) column (2 outputs): staging 2 divergent
//      loads/thread (was 8), j-loop = {R1-exact coeff cos, b64 broadcast, 2 fma}.
//      Per-output j-chains use R1's exact f32 expression sequence -> bit-identical out;
//      only stats partial grouping changes (verified safe, R13/R14).

#define HALF_N 262144  // 512*512 per-batch elements
#define PI_F 3.14159274101257324f

// ws layout (floats): Vt [0..524288) [j][b][t]; partial [524288..526336) 512 x {s0,q0,s1,q1}

__device__ __forceinline__ uint32_t rotl32(uint32_t v, int r) {
  return (v << r) | (v >> (32 - r));
}

// XLA ErfInv32 (Giles) -- matches reference's lax.erf_inv
__device__ __forceinline__ float erfinv_xla(float x) {
  float w = -log1pf(__fmul_rn(-x, x));
  float p;
  if (w < 5.0f) {
    w = w - 2.5f;
    p = 2.81022636e-08f;
    p = fmaf(p, w, 3.43273939e-07f);
    p = fmaf(p, w, -3.5233877e-06f);
    p = fmaf(p, w, -4.39150654e-06f);
    p = fmaf(p, w, 0.00021858087f);
    p = fmaf(p, w, -0.00125372503f);
    p = fmaf(p, w, -0.00417768164f);
    p = fmaf(p, w, 0.246640727f);
    p = fmaf(p, w, 1.50140941f);
  } else {
    w = __fsqrt_rn(w) - 3.0f;
    p = -0.000200214257f;
    p = fmaf(p, w, 0.000100950558f);
    p = fmaf(p, w, 0.00134934322f);
    p = fmaf(p, w, -0.00367342844f);
    p = fmaf(p, w, 0.00573950773f);
    p = fmaf(p, w, -0.0076224613f);
    p = fmaf(p, w, 0.00943887047f);
    p = fmaf(p, w, 1.00167406f);
    p = fmaf(p, w, 2.83297682f);
  }
  return p * x;
}

// Cy[k,n] = sc(k) * 2 * cos(pi*(2n+1)*k/1024), with n2p1 = (float)(2n+1) exact
__device__ __forceinline__ float cy_elem(float n2p1, float kf, float sc) {
  float t1 = __fmul_rn(PI_F, n2p1);
  float arg = __fmul_rn(t1, kf) * (1.0f / 1024.0f);
  return __fmul_rn(sc, __fmul_rn(2.0f, __cosf(arg)));
}

// fusedB, block = j (grid 512, 512 threads):  [R1-verified, byte-identical]
//   A  (tid<128): cyl[jj] = Cy[j,128+jj]
//   A2 (tid<256): us[b*128+i] = sum_jj x[b,i,jj]*cyl[jj]
//   B  (lane=k):  msf[2k+b] = a[k] * sum_i Cy[k,i]*us[b,i]; fs[k] = F[k,j]
//   C  (lane=t):  Vt[j,b,t] = sum_k cos(fs[k]*t) * msf[2k+b]
__global__ __launch_bounds__(512, 4) void stageB_kernel(const float* __restrict__ x,
                                                        float* __restrict__ Vt) {
  __shared__ float cyl[128];
  __shared__ float us[256];
  __shared__ float fs[512];
  __shared__ float msf[1024];
  int j = blockIdx.x;
  int tid = threadIdx.x;
  float jf = (float)j;
  if (tid < 128) {
    float scj = (j == 0) ? (1.0f / __fsqrt_rn(2048.0f)) : 0.03125f;
    cyl[tid] = cy_elem((float)(2 * (128 + tid) + 1), jf, scj);
  }
  __syncthreads();
  if (tid < 256) {
    int b = tid >> 7, i = tid & 127;
    const float* xr = x + (b * 128 + i) * 128;
    float accA = 0.0f, accB = 0.0f;
    for (int jj = 0; jj < 128; jj += 8) {
      float4 xa = *(const float4*)&xr[jj];
      float4 xb = *(const float4*)&xr[jj + 4];
      float4 ca = *(const float4*)&cyl[jj];
      float4 cb = *(const float4*)&cyl[jj + 4];
      accA = fmaf(xa.x, ca.x, accA); accB = fmaf(xa.y, ca.y, accB);
      accA = fmaf(xa.z, ca.z, accA); accB = fmaf(xa.w, ca.w, accB);
      accA = fmaf(xb.x, cb.x, accA); accB = fmaf(xb.y, cb.y, accB);
      accA = fmaf(xb.z, cb.z, accA); accB = fmaf(xb.w, cb.w, accB);
    }
    us[tid] = accA + accB;
  }
  __syncthreads();
  {
    float kf = (float)tid;
    float sc = (tid == 0) ? (1.0f / __fsqrt_rn(2048.0f)) : 0.03125f;
    float a = cy_elem(1.0f, kf, sc);  // i=0: a[k] = Cy[k,0]
    float acc0 = __fmul_rn(a, us[0]);
    float acc1 = __fmul_rn(a, us[128]);
    // i = 1..3 singles, then aligned batches of 4
    float accA0 = 0.f, accA1 = 0.f;
    {
      float c1 = cy_elem(3.0f, kf, sc);
      float c2 = cy_elem(5.0f, kf, sc);
      float c3 = cy_elem(7.0f, kf, sc);
      acc0 = fmaf(c1, us[1], acc0);   acc1 = fmaf(c1, us[129], acc1);
      accA0 = fmaf(c2, us[2], accA0); accA1 = fmaf(c2, us[130], accA1);
      acc0 = fmaf(c3, us[3], acc0);   acc1 = fmaf(c3, us[131], acc1);
    }
    for (int i = 4; i < 128; i += 4) {
      float b0 = (float)(2 * i + 1);
      float c0 = cy_elem(b0, kf, sc);
      float c1 = cy_elem(__fadd_rn(b0, 2.0f), kf, sc);
      float c2 = cy_elem(__fadd_rn(b0, 4.0f), kf, sc);
      float c3 = cy_elem(__fadd_rn(b0, 6.0f), kf, sc);
      float4 u0 = *(const float4*)&us[i];
      float4 u1 = *(const float4*)&us[128 + i];
      acc0 = fmaf(c0, u0.x, acc0);   acc1 = fmaf(c0, u1.x, acc1);
      accA0 = fmaf(c1, u0.y, accA0); accA1 = fmaf(c1, u1.y, accA1);
      acc0 = fmaf(c2, u0.z, acc0);   acc1 = fmaf(c2, u1.z, acc1);
      accA0 = fmaf(c3, u0.w, accA0); accA1 = fmaf(c3, u1.w, accA1);
    }
    acc0 += accA0;
    acc1 += accA1;
    const float w0 = PI_F / 512.0f;  // exact pow2 scale of pi_f
    float ky = __fmul_rn(kf, w0);
    float kx = __fmul_rn(jf, w0);
    fs[tid] = __fsqrt_rn(__fadd_rn(__fmul_rn(ky, ky), __fmul_rn(kx, kx)));
    msf[2 * tid] = __fmul_rn(a, acc0);
    msf[2 * tid + 1] = __fmul_rn(a, acc1);
  }
  __syncthreads();
  float tf = (float)tid;
  float acc0 = 0.f, acc1 = 0.f, acc2 = 0.f, acc3 = 0.f;
  for (int k0 = 0; k0 < 512; k0 += 8) {
    float4 f0 = *(const float4*)&fs[k0];
    float4 f1 = *(const float4*)&fs[k0 + 4];
    float4 m0 = *(const float4*)&msf[2 * k0];
    float4 m1 = *(const float4*)&msf[2 * k0 + 4];
    float4 m2 = *(const float4*)&msf[2 * k0 + 8];
    float4 m3 = *(const float4*)&msf[2 * k0 + 12];
    float ph0 = __cosf(__fmul_rn(f0.x, tf));  // arg bit-matches ref's f32 F*t
    float ph1 = __cosf(__fmul_rn(f0.y, tf));
    float ph2 = __cosf(__fmul_rn(f0.z, tf));
    float ph3 = __cosf(__fmul_rn(f0.w, tf));
    float ph4 = __cosf(__fmul_rn(f1.x, tf));
    float ph5 = __cosf(__fmul_rn(f1.y, tf));
    float ph6 = __cosf(__fmul_rn(f1.z, tf));
    float ph7 = __cosf(__fmul_rn(f1.w, tf));
    acc0 = fmaf(ph0, m0.x, acc0); acc1 = fmaf(ph0, m0.y, acc1);
    acc2 = fmaf(ph1, m0.z, acc2); acc3 = fmaf(ph1, m0.w, acc3);
    acc0 = fmaf(ph2, m1.x, acc0); acc1 = fmaf(ph2, m1.y, acc1);
    acc2 = fmaf(ph3, m1.z, acc2); acc3 = fmaf(ph3, m1.w, acc3);
    acc0 = fmaf(ph4, m2.x, acc0); acc1 = fmaf(ph4, m2.y, acc1);
    acc2 = fmaf(ph5, m2.z, acc2); acc3 = fmaf(ph5, m2.w, acc3);
    acc0 = fmaf(ph6, m3.x, acc0); acc1 = fmaf(ph6, m3.y, acc1);
    acc2 = fmaf(ph7, m3.z, acc2); acc3 = fmaf(ph7, m3.w, acc3);
  }
  Vt[(j << 10) + tid] = acc0 + acc2;
  Vt[(j << 10) + 512 + tid] = acc1 + acc3;
}

// stageC: block = t (grid 512, 512 threads), thread = l; outputs {b0,b1}.
//   out[b,t,l] = (1/3) * sum_j Cy[j,l] * Vt[j,b,t]
//   vq[j][2] = {Vt[j][b0][t], Vt[j][b1][t]} staged (2 divergent loads/thread, once);
//   j-loop: R1-exact coefficient cos + b64 broadcast + 2 fma. 50% occupancy.
__global__ __launch_bounds__(512, 4) void stageC_kernel(const float* __restrict__ Vt,
                                                        float* __restrict__ out,
                                                        float* __restrict__ partial) {
  __shared__ float vq[1024];  // [j][2] = {b0, b1} for this block's t
  int t = blockIdx.x;
  int tid = threadIdx.x;
  vq[2 * tid] = Vt[(tid << 10) + t];
  vq[2 * tid + 1] = Vt[(tid << 10) + 512 + t];
  __syncthreads();
  int l = tid;
  float t1 = __fmul_rn(PI_F, (float)(2 * l + 1));
  float cy0 = __fmul_rn(1.0f / __fsqrt_rn(2048.0f), 2.0f);  // j=0: s0*2*cos(0)
  float2 v0 = *(const float2*)&vq[0];
  float a0 = __fmul_rn(cy0, v0.x);
  float a1 = __fmul_rn(cy0, v0.y);
  // j = 1..3 singles, then aligned batches of 4 (R1-exact arg expressions)
  for (int j = 1; j < 4; ++j) {
    float arg = __fmul_rn(t1, (float)j) * (1.0f / 1024.0f);
    float c = __fmul_rn(0.0625f, __cosf(arg));
    float2 v = *(const float2*)&vq[j << 1];
    a0 = fmaf(c, v.x, a0);
    a1 = fmaf(c, v.y, a1);
  }
  for (int j = 4; j < 512; j += 4) {
    float jb = (float)j;
    float c0 = __fmul_rn(0.0625f, __cosf(__fmul_rn(t1, jb) * (1.0f / 1024.0f)));
    float c1 = __fmul_rn(0.0625f, __cosf(__fmul_rn(t1, __fadd_rn(jb, 1.0f)) * (1.0f / 1024.0f)));
    float c2 = __fmul_rn(0.0625f, __cosf(__fmul_rn(t1, __fadd_rn(jb, 2.0f)) * (1.0f / 1024.0f)));
    float c3 = __fmul_rn(0.0625f, __cosf(__fmul_rn(t1, __fadd_rn(jb, 3.0f)) * (1.0f / 1024.0f)));
    float2 va = *(const float2*)&vq[j << 1];
    float2 vb = *(const float2*)&vq[(j + 1) << 1];
    float2 vc = *(const float2*)&vq[(j + 2) << 1];
    float2 vd = *(const float2*)&vq[(j + 3) << 1];
    a0 = fmaf(c0, va.x, a0); a1 = fmaf(c0, va.y, a1);
    a0 = fmaf(c1, vb.x, a0); a1 = fmaf(c1, vb.y, a1);
    a0 = fmaf(c2, vc.x, a0); a1 = fmaf(c2, vc.y, a1);
    a0 = fmaf(c3, vd.x, a0); a1 = fmaf(c3, vd.y, a1);
  }
  float p0 = a0 / 3.0f, p1 = a1 / 3.0f;
  out[(t << 9) + l] = p0;
  out[HALF_N + (t << 9) + l] = p1;
  // stats partials (grouping differs from R1 -- verified-safe class)
  float s0 = p0, q0 = p0 * p0;
  float s1 = p1, q1 = p1 * p1;
  for (int off = 32; off > 0; off >>= 1) {
    s0 += __shfl_down(s0, off);
    q0 += __shfl_down(q0, off);
    s1 += __shfl_down(s1, off);
    q1 += __shfl_down(q1, off);
  }
  __shared__ float red[8][4];
  int wave = tid >> 6;
  if ((tid & 63) == 0) {
    red[wave][0] = s0; red[wave][1] = q0; red[wave][2] = s1; red[wave][3] = q1;
  }
  __syncthreads();
  if (tid == 0) {
    float c0 = 0.f, c1 = 0.f, c2 = 0.f, c3 = 0.f;
    for (int wv = 0; wv < 8; ++wv) {
      c0 += red[wv][0]; c1 += red[wv][1]; c2 += red[wv][2]; c3 += red[wv][3];
    }
    partial[blockIdx.x * 4 + 0] = c0;
    partial[blockIdx.x * 4 + 1] = c1;
    partial[blockIdx.x * 4 + 2] = c2;
    partial[blockIdx.x * 4 + 3] = c3;
  }
}

// Fused stats + noise: redundant partial reduce (512 quads) -> (std0,std1), then threefry noise.
// element i -> threefry2x32(key=(0,42), ctr=(0,i)), bits = o0^o1
__global__ __launch_bounds__(256) void noise_kernel(float* __restrict__ out,
                                                    const float* __restrict__ partial) {
  int tid = threadIdx.x;
  const float4* pq = (const float4*)partial;  // 512 quads {s0,q0,s1,q1}
  float4 pa = pq[tid];
  float4 pb = pq[tid + 256];
  float s0 = pa.x + pb.x, q0 = pa.y + pb.y, s1 = pa.z + pb.z, q1 = pa.w + pb.w;
  for (int off = 32; off > 0; off >>= 1) {
    s0 += __shfl_down(s0, off);
    q0 += __shfl_down(q0, off);
    s1 += __shfl_down(s1, off);
    q1 += __shfl_down(q1, off);
  }
  __shared__ float red[4][4];
  int wave = tid >> 6;
  if ((tid & 63) == 0) {
    red[wave][0] = s0; red[wave][1] = q0; red[wave][2] = s1; red[wave][3] = q1;
  }
  __syncthreads();
  float S = red[0][0] + red[1][0] + red[2][0] + red[3][0];
  float Q = red[0][1] + red[1][1] + red[2][1] + red[3][1];
  float S2 = red[0][2] + red[1][2] + red[2][2] + red[3][2];
  float Q2 = red[0][3] + red[1][3] + red[2][3] + red[3][3];
  const float invN = 1.0f / 262144.0f;
  float m0 = S * invN, m1 = S2 * invN;
  float std0 = __fsqrt_rn(fmaxf(Q * invN - m0 * m0, 0.0f));
  float std1 = __fsqrt_rn(fmaxf(Q2 * invN - m1 * m1, 0.0f));

  int i = blockIdx.x * 256 + tid;  // < 524288
  uint32_t x0 = 0u;
  uint32_t x1 = (uint32_t)i;
  const uint32_t k0 = 0u, k1 = 42u;
  const uint32_t k2 = k0 ^ k1 ^ 0x1BD11BDAu;
  x0 += k0; x1 += k1;
#define QR(r) x0 += x1; x1 = rotl32(x1, r); x1 ^= x0;
  QR(13) QR(15) QR(26) QR(6)
  x0 += k1; x1 += k2 + 1u;
  QR(17) QR(29) QR(16) QR(24)
  x0 += k2; x1 += k0 + 2u;
  QR(13) QR(15) QR(26) QR(6)
  x0 += k0; x1 += k1 + 3u;
  QR(17) QR(29) QR(16) QR(24)
  x0 += k1; x1 += k2 + 4u;
  QR(13) QR(15) QR(26) QR(6)
  x0 += k2; x1 += k0 + 5u;
#undef QR
  uint32_t bits = x0 ^ x1;
  const float lo = __uint_as_float(0xBF7FFFFFu);  // nextafter(-1,0)
  float f = __uint_as_float((bits >> 9) | 0x3F800000u) - 1.0f;
  float u = fmaxf(lo, __fadd_rn(__fmul_rn(f, 2.0f), lo));
  const float sqrt2 = 1.41421356237309515f;
  out[i] += (i < HALF_N ? std0 : std1) * (sqrt2 * erfinv_xla(u));
}

extern "C" void kernel_launch(void* const* d_in, const int* in_sizes, int n_in,
                              void* d_out, int out_size, void* d_ws, size_t ws_size,
                              hipStream_t stream) {
  const float* x = (const float*)d_in[0];
  float* ws = (float*)d_ws;
  float* Vt      = ws;
  float* partial = ws + 524288;
  float* out = (float*)d_out;

  stageB_kernel<<<512, 512, 0, stream>>>(x, Vt);
  stageC_kernel<<<512, 512, 0, stream>>>(Vt, out, partial);
  noise_kernel<<<2048, 256, 0, stream>>>(out, partial);
}

// Round 8
// 118.522 us; speedup vs baseline: 1.7918x; 1.1093x over previous
//
#include <hip/hip_runtime.h>
#include <stdint.h>
#include <math.h>

// PhysicsForwardModel: B=2, Nz=Nx=128, Ly=Lx=512.
// out[b,t,l] = (1/3) * sum_j Cy[j,l] * sum_k cos(F[k,j]*t) * a[k] * (Cy[:,:128] x[b] Cy[:,128:256]^T)[k,j]
//              + std_b * N(0,1)  (JAX threefry key=42, partitionable counters, XLA erfinv)
// R17: stageB/noise = R1's verified kernels byte-for-byte. ONE change: stageC's coefficient
//      cos(theta_l * j) is linear-phase in j -> Chebyshev recurrence c_j = 2cos(th)*c_{j-1} -
//      c_{j-2} (1 fma) with bit-identical __cosf anchors every 16 j (<=14 recurred steps,
//      |U_n|<=n+1 => coeff err ~1e-5 << 2e-3 budget). 0.0625 is an exact pow2: accumulate raw
//      cos and scale once (fma chains commute exactly with pow2 scaling); j=0 term pre-scaled
//      by exact 16. Trans work in stageC drops 512 -> 64 cos per thread.

#define HALF_N 262144  // 512*512 per-batch elements
#define PI_F 3.14159274101257324f

// ws layout (floats): Vt [0..524288) [j][b][t]; partial [524288..526336) 512 x {s0,q0,s1,q1}

__device__ __forceinline__ uint32_t rotl32(uint32_t v, int r) {
  return (v << r) | (v >> (32 - r));
}

// XLA ErfInv32 (Giles) -- matches reference's lax.erf_inv
__device__ __forceinline__ float erfinv_xla(float x) {
  float w = -log1pf(__fmul_rn(-x, x));
  float p;
  if (w < 5.0f) {
    w = w - 2.5f;
    p = 2.81022636e-08f;
    p = fmaf(p, w, 3.43273939e-07f);
    p = fmaf(p, w, -3.5233877e-06f);
    p = fmaf(p, w, -4.39150654e-06f);
    p = fmaf(p, w, 0.00021858087f);
    p = fmaf(p, w, -0.00125372503f);
    p = fmaf(p, w, -0.00417768164f);
    p = fmaf(p, w, 0.246640727f);
    p = fmaf(p, w, 1.50140941f);
  } else {
    w = __fsqrt_rn(w) - 3.0f;
    p = -0.000200214257f;
    p = fmaf(p, w, 0.000100950558f);
    p = fmaf(p, w, 0.00134934322f);
    p = fmaf(p, w, -0.00367342844f);
    p = fmaf(p, w, 0.00573950773f);
    p = fmaf(p, w, -0.0076224613f);
    p = fmaf(p, w, 0.00943887047f);
    p = fmaf(p, w, 1.00167406f);
    p = fmaf(p, w, 2.83297682f);
  }
  return p * x;
}

// Cy[k,n] = sc(k) * 2 * cos(pi*(2n+1)*k/1024), with n2p1 = (float)(2n+1) exact
__device__ __forceinline__ float cy_elem(float n2p1, float kf, float sc) {
  float t1 = __fmul_rn(PI_F, n2p1);
  float arg = __fmul_rn(t1, kf) * (1.0f / 1024.0f);
  return __fmul_rn(sc, __fmul_rn(2.0f, __cosf(arg)));
}

// fusedB, block = j (grid 512, 512 threads):  [R1-verified, byte-identical]
__global__ __launch_bounds__(512, 4) void stageB_kernel(const float* __restrict__ x,
                                                        float* __restrict__ Vt) {
  __shared__ float cyl[128];
  __shared__ float us[256];
  __shared__ float fs[512];
  __shared__ float msf[1024];
  int j = blockIdx.x;
  int tid = threadIdx.x;
  float jf = (float)j;
  if (tid < 128) {
    float scj = (j == 0) ? (1.0f / __fsqrt_rn(2048.0f)) : 0.03125f;
    cyl[tid] = cy_elem((float)(2 * (128 + tid) + 1), jf, scj);
  }
  __syncthreads();
  if (tid < 256) {
    int b = tid >> 7, i = tid & 127;
    const float* xr = x + (b * 128 + i) * 128;
    float accA = 0.0f, accB = 0.0f;
    for (int jj = 0; jj < 128; jj += 8) {
      float4 xa = *(const float4*)&xr[jj];
      float4 xb = *(const float4*)&xr[jj + 4];
      float4 ca = *(const float4*)&cyl[jj];
      float4 cb = *(const float4*)&cyl[jj + 4];
      accA = fmaf(xa.x, ca.x, accA); accB = fmaf(xa.y, ca.y, accB);
      accA = fmaf(xa.z, ca.z, accA); accB = fmaf(xa.w, ca.w, accB);
      accA = fmaf(xb.x, cb.x, accA); accB = fmaf(xb.y, cb.y, accB);
      accA = fmaf(xb.z, cb.z, accA); accB = fmaf(xb.w, cb.w, accB);
    }
    us[tid] = accA + accB;
  }
  __syncthreads();
  {
    float kf = (float)tid;
    float sc = (tid == 0) ? (1.0f / __fsqrt_rn(2048.0f)) : 0.03125f;
    float a = cy_elem(1.0f, kf, sc);  // i=0: a[k] = Cy[k,0]
    float acc0 = __fmul_rn(a, us[0]);
    float acc1 = __fmul_rn(a, us[128]);
    // i = 1..3 singles, then aligned batches of 4
    float accA0 = 0.f, accA1 = 0.f;
    {
      float c1 = cy_elem(3.0f, kf, sc);
      float c2 = cy_elem(5.0f, kf, sc);
      float c3 = cy_elem(7.0f, kf, sc);
      acc0 = fmaf(c1, us[1], acc0);   acc1 = fmaf(c1, us[129], acc1);
      accA0 = fmaf(c2, us[2], accA0); accA1 = fmaf(c2, us[130], accA1);
      acc0 = fmaf(c3, us[3], acc0);   acc1 = fmaf(c3, us[131], acc1);
    }
    for (int i = 4; i < 128; i += 4) {
      float b0 = (float)(2 * i + 1);
      float c0 = cy_elem(b0, kf, sc);
      float c1 = cy_elem(__fadd_rn(b0, 2.0f), kf, sc);
      float c2 = cy_elem(__fadd_rn(b0, 4.0f), kf, sc);
      float c3 = cy_elem(__fadd_rn(b0, 6.0f), kf, sc);
      float4 u0 = *(const float4*)&us[i];
      float4 u1 = *(const float4*)&us[128 + i];
      acc0 = fmaf(c0, u0.x, acc0);   acc1 = fmaf(c0, u1.x, acc1);
      accA0 = fmaf(c1, u0.y, accA0); accA1 = fmaf(c1, u1.y, accA1);
      acc0 = fmaf(c2, u0.z, acc0);   acc1 = fmaf(c2, u1.z, acc1);
      accA0 = fmaf(c3, u0.w, accA0); accA1 = fmaf(c3, u1.w, accA1);
    }
    acc0 += accA0;
    acc1 += accA1;
    const float w0 = PI_F / 512.0f;  // exact pow2 scale of pi_f
    float ky = __fmul_rn(kf, w0);
    float kx = __fmul_rn(jf, w0);
    fs[tid] = __fsqrt_rn(__fadd_rn(__fmul_rn(ky, ky), __fmul_rn(kx, kx)));
    msf[2 * tid] = __fmul_rn(a, acc0);
    msf[2 * tid + 1] = __fmul_rn(a, acc1);
  }
  __syncthreads();
  float tf = (float)tid;
  float acc0 = 0.f, acc1 = 0.f, acc2 = 0.f, acc3 = 0.f;
  for (int k0 = 0; k0 < 512; k0 += 8) {
    float4 f0 = *(const float4*)&fs[k0];
    float4 f1 = *(const float4*)&fs[k0 + 4];
    float4 m0 = *(const float4*)&msf[2 * k0];
    float4 m1 = *(const float4*)&msf[2 * k0 + 4];
    float4 m2 = *(const float4*)&msf[2 * k0 + 8];
    float4 m3 = *(const float4*)&msf[2 * k0 + 12];
    float ph0 = __cosf(__fmul_rn(f0.x, tf));  // arg bit-matches ref's f32 F*t
    float ph1 = __cosf(__fmul_rn(f0.y, tf));
    float ph2 = __cosf(__fmul_rn(f0.z, tf));
    float ph3 = __cosf(__fmul_rn(f0.w, tf));
    float ph4 = __cosf(__fmul_rn(f1.x, tf));
    float ph5 = __cosf(__fmul_rn(f1.y, tf));
    float ph6 = __cosf(__fmul_rn(f1.z, tf));
    float ph7 = __cosf(__fmul_rn(f1.w, tf));
    acc0 = fmaf(ph0, m0.x, acc0); acc1 = fmaf(ph0, m0.y, acc1);
    acc2 = fmaf(ph1, m0.z, acc2); acc3 = fmaf(ph1, m0.w, acc3);
    acc0 = fmaf(ph2, m1.x, acc0); acc1 = fmaf(ph2, m1.y, acc1);
    acc2 = fmaf(ph3, m1.z, acc2); acc3 = fmaf(ph3, m1.w, acc3);
    acc0 = fmaf(ph4, m2.x, acc0); acc1 = fmaf(ph4, m2.y, acc1);
    acc2 = fmaf(ph5, m2.z, acc2); acc3 = fmaf(ph5, m2.w, acc3);
    acc0 = fmaf(ph6, m3.x, acc0); acc1 = fmaf(ph6, m3.y, acc1);
    acc2 = fmaf(ph7, m3.z, acc2); acc3 = fmaf(ph7, m3.w, acc3);
  }
  Vt[(j << 10) + tid] = acc0 + acc2;
  Vt[(j << 10) + 512 + tid] = acc1 + acc3;
}

// stageC: block = (t-pair, l-half) (grid 512, 256 threads). R1 structure; coefficients via
// Chebyshev recurrence with __cosf anchors every 16 j (anchor args bit-match R1's exprs).
// Accumulates RAW cos (16x ref scale); final exact *0.0625 restores ref's chain bitwise
// (modulo the ~1e-5 recurred-coefficient deltas).
__global__ __launch_bounds__(256, 4) void stageC_kernel(const float* __restrict__ Vt,
                                                        float* __restrict__ out,
                                                        float* __restrict__ partial) {
  __shared__ float vq[2048];  // [j][4] = {b0t0, b1t0, b0t1, b1t1}
  int tpair = blockIdx.x >> 1;
  int lhalf = blockIdx.x & 1;
  int t0 = tpair << 1;
  int tid = threadIdx.x;
#pragma unroll
  for (int r = 0; r < 2; ++r) {
    int j = tid + (r << 8);
    const float* base = Vt + (j << 10);
    vq[(j << 2) + 0] = base[t0];
    vq[(j << 2) + 1] = base[512 + t0];
    vq[(j << 2) + 2] = base[t0 + 1];
    vq[(j << 2) + 3] = base[512 + t0 + 1];
  }
  __syncthreads();
  int l = (lhalf << 8) + tid;
  float t1 = __fmul_rn(PI_F, (float)(2 * l + 1));
  // step cosine: theta = t1/1024; k2 = 2*cos(theta). Also the j=1 anchor (same expr as R1).
  float cth = __cosf(__fmul_rn(t1, 1.0f) * (1.0f / 1024.0f));
  float k2 = cth + cth;  // exact *2
  // j=0 term, pre-scaled by exact 16 (cy0*16 exact; fmul(16c,v)=16*fmul(c,v) exact)
  float cy0 = __fmul_rn(1.0f / __fsqrt_rn(2048.0f), 2.0f);
  float c16 = __fmul_rn(cy0, 16.0f);
  float4 v0 = *(const float4*)&vq[0];
  float a00 = __fmul_rn(c16, v0.x);
  float a01 = __fmul_rn(c16, v0.y);
  float a10 = __fmul_rn(c16, v0.z);
  float a11 = __fmul_rn(c16, v0.w);
  float c_m1, c_m2;  // cos at j-1, j-2 (raw, unscaled)
  {
    // j=1 anchor (cth), j=2 anchor, then recur j=3..15
    float4 v1 = *(const float4*)&vq[1 << 2];
    a00 = fmaf(cth, v1.x, a00); a01 = fmaf(cth, v1.y, a01);
    a10 = fmaf(cth, v1.z, a10); a11 = fmaf(cth, v1.w, a11);
    float c2v = __cosf(__fmul_rn(t1, 2.0f) * (1.0f / 1024.0f));
    float4 v2 = *(const float4*)&vq[2 << 2];
    a00 = fmaf(c2v, v2.x, a00); a01 = fmaf(c2v, v2.y, a01);
    a10 = fmaf(c2v, v2.z, a10); a11 = fmaf(c2v, v2.w, a11);
    c_m2 = cth; c_m1 = c2v;
#pragma unroll
    for (int j = 3; j < 16; ++j) {
      float cn = fmaf(k2, c_m1, -c_m2);
      float4 v = *(const float4*)&vq[j << 2];
      a00 = fmaf(cn, v.x, a00); a01 = fmaf(cn, v.y, a01);
      a10 = fmaf(cn, v.z, a10); a11 = fmaf(cn, v.w, a11);
      c_m2 = c_m1; c_m1 = cn;
    }
  }
  for (int j0 = 16; j0 < 512; j0 += 16) {
    float jb = (float)j0;
    // anchors: args bit-match R1's coefficient expressions
    float ca = __cosf(__fmul_rn(t1, jb) * (1.0f / 1024.0f));
    float cb = __cosf(__fmul_rn(t1, __fadd_rn(jb, 1.0f)) * (1.0f / 1024.0f));
    float4 va = *(const float4*)&vq[j0 << 2];
    a00 = fmaf(ca, va.x, a00); a01 = fmaf(ca, va.y, a01);
    a10 = fmaf(ca, va.z, a10); a11 = fmaf(ca, va.w, a11);
    float4 vb = *(const float4*)&vq[(j0 + 1) << 2];
    a00 = fmaf(cb, vb.x, a00); a01 = fmaf(cb, vb.y, a01);
    a10 = fmaf(cb, vb.z, a10); a11 = fmaf(cb, vb.w, a11);
    c_m2 = ca; c_m1 = cb;
#pragma unroll
    for (int n = 2; n < 16; ++n) {
      float cn = fmaf(k2, c_m1, -c_m2);
      float4 v = *(const float4*)&vq[(j0 + n) << 2];
      a00 = fmaf(cn, v.x, a00); a01 = fmaf(cn, v.y, a01);
      a10 = fmaf(cn, v.z, a10); a11 = fmaf(cn, v.w, a11);
      c_m2 = c_m1; c_m1 = cn;
    }
  }
  // exact pow2 rescale, then /3 (same final op as R1)
  float p00 = __fmul_rn(a00, 0.0625f) / 3.0f;
  float p01 = __fmul_rn(a01, 0.0625f) / 3.0f;
  float p10 = __fmul_rn(a10, 0.0625f) / 3.0f;
  float p11 = __fmul_rn(a11, 0.0625f) / 3.0f;
  out[(t0 << 9) + l] = p00;
  out[((t0 + 1) << 9) + l] = p10;
  out[HALF_N + (t0 << 9) + l] = p01;
  out[HALF_N + ((t0 + 1) << 9) + l] = p11;
  float s0 = p00 + p10, q0 = fmaf(p00, p00, p10 * p10);
  float s1 = p01 + p11, q1 = fmaf(p01, p01, p11 * p11);
  for (int off = 32; off > 0; off >>= 1) {
    s0 += __shfl_down(s0, off);
    q0 += __shfl_down(q0, off);
    s1 += __shfl_down(s1, off);
    q1 += __shfl_down(q1, off);
  }
  __shared__ float red[4][4];
  int wave = tid >> 6;
  if ((tid & 63) == 0) {
    red[wave][0] = s0; red[wave][1] = q0; red[wave][2] = s1; red[wave][3] = q1;
  }
  __syncthreads();
  if (tid == 0) {
    float a0 = 0.f, a1 = 0.f, a2 = 0.f, a3 = 0.f;
    for (int wv = 0; wv < 4; ++wv) {
      a0 += red[wv][0]; a1 += red[wv][1]; a2 += red[wv][2]; a3 += red[wv][3];
    }
    partial[blockIdx.x * 4 + 0] = a0;
    partial[blockIdx.x * 4 + 1] = a1;
    partial[blockIdx.x * 4 + 2] = a2;
    partial[blockIdx.x * 4 + 3] = a3;
  }
}

// Fused stats + noise: redundant partial reduce (512 quads) -> (std0,std1), then threefry noise.
// element i -> threefry2x32(key=(0,42), ctr=(0,i)), bits = o0^o1
__global__ __launch_bounds__(256) void noise_kernel(float* __restrict__ out,
                                                    const float* __restrict__ partial) {
  int tid = threadIdx.x;
  const float4* pq = (const float4*)partial;  // 512 quads {s0,q0,s1,q1}
  float4 pa = pq[tid];
  float4 pb = pq[tid + 256];
  float s0 = pa.x + pb.x, q0 = pa.y + pb.y, s1 = pa.z + pb.z, q1 = pa.w + pb.w;
  for (int off = 32; off > 0; off >>= 1) {
    s0 += __shfl_down(s0, off);
    q0 += __shfl_down(q0, off);
    s1 += __shfl_down(s1, off);
    q1 += __shfl_down(q1, off);
  }
  __shared__ float red[4][4];
  int wave = tid >> 6;
  if ((tid & 63) == 0) {
    red[wave][0] = s0; red[wave][1] = q0; red[wave][2] = s1; red[wave][3] = q1;
  }
  __syncthreads();
  float S = red[0][0] + red[1][0] + red[2][0] + red[3][0];
  float Q = red[0][1] + red[1][1] + red[2][1] + red[3][1];
  float S2 = red[0][2] + red[1][2] + red[2][2] + red[3][2];
  float Q2 = red[0][3] + red[1][3] + red[2][3] + red[3][3];
  const float invN = 1.0f / 262144.0f;
  float m0 = S * invN, m1 = S2 * invN;
  float std0 = __fsqrt_rn(fmaxf(Q * invN - m0 * m0, 0.0f));
  float std1 = __fsqrt_rn(fmaxf(Q2 * invN - m1 * m1, 0.0f));

  int i = blockIdx.x * 256 + tid;  // < 524288
  uint32_t x0 = 0u;
  uint32_t x1 = (uint32_t)i;
  const uint32_t k0 = 0u, k1 = 42u;
  const uint32_t k2 = k0 ^ k1 ^ 0x1BD11BDAu;
  x0 += k0; x1 += k1;
#define QR(r) x0 += x1; x1 = rotl32(x1, r); x1 ^= x0;
  QR(13) QR(15) QR(26) QR(6)
  x0 += k1; x1 += k2 + 1u;
  QR(17) QR(29) QR(16) QR(24)
  x0 += k2; x1 += k0 + 2u;
  QR(13) QR(15) QR(26) QR(6)
  x0 += k0; x1 += k1 + 3u;
  QR(17) QR(29) QR(16) QR(24)
  x0 += k1; x1 += k2 + 4u;
  QR(13) QR(15) QR(26) QR(6)
  x0 += k2; x1 += k0 + 5u;
#undef QR
  uint32_t bits = x0 ^ x1;
  const float lo = __uint_as_float(0xBF7FFFFFu);  // nextafter(-1,0)
  float f = __uint_as_float((bits >> 9) | 0x3F800000u) - 1.0f;
  float u = fmaxf(lo, __fadd_rn(__fmul_rn(f, 2.0f), lo));
  const float sqrt2 = 1.41421356237309515f;
  out[i] += (i < HALF_N ? std0 : std1) * (sqrt2 * erfinv_xla(u));
}

extern "C" void kernel_launch(void* const* d_in, const int* in_sizes, int n_in,
                              void* d_out, int out_size, void* d_ws, size_t ws_size,
                              hipStream_t stream) {
  const float* x = (const float*)d_in[0];
  float* ws = (float*)d_ws;
  float* Vt      = ws;
  float* partial = ws + 524288;
  float* out = (float*)d_out;

  stageB_kernel<<<512, 512, 0, stream>>>(x, Vt);
  stageC_kernel<<<512, 256, 0, stream>>>(Vt, out, partial);
  noise_kernel<<<2048, 256, 0, stream>>>(out, partial);
}